// Round 8
// baseline (215.266 us; speedup 1.0000x reference)
//
#include <hip/hip_runtime.h>
#include <hip/hip_bf16.h>
#include <cstdint>
#include <cmath>

#define DIMC   192
#define DSTATE 16
#define DCONV  4
#define DINNER 384
#define DTRANK 12
#define BSZ    4
#define HSP    64
#define WSP    64
#define LSEQ   4096
#define NTOK   (BSZ*LSEQ)            // 16384
#define XZW    (2*DINNER)            // 768
#define LC4    16                    // scan chunk length
#define NCH4   (LSEQ/LC4)            // 256 chunks per batch
#define NXP    512                   // padded fused x_proj+dt output width

typedef unsigned short ushortT;
using short8 = __attribute__((ext_vector_type(8))) short;
using f32x4  = __attribute__((ext_vector_type(4))) float;

__device__ __forceinline__ float bflo(unsigned u) { return __uint_as_float(u << 16); }
__device__ __forceinline__ float bfhi(unsigned u) { return __uint_as_float(u & 0xffff0000u); }
__device__ __forceinline__ float bf2f(ushortT u) { return __uint_as_float(((unsigned)u) << 16); }
__device__ __forceinline__ unsigned pkbf(float lo, float hi) {
  __hip_bfloat16 l = __float2bfloat16(lo), h = __float2bfloat16(hi);
  return (unsigned)*(ushortT*)&l | ((unsigned)*(ushortT*)&h << 16);
}
#define UNPK8(arr, base, v4)                                        \
  arr[base + 0] = bflo(v4.x); arr[base + 1] = bfhi(v4.x);           \
  arr[base + 2] = bflo(v4.y); arr[base + 3] = bfhi(v4.y);           \
  arr[base + 4] = bflo(v4.z); arr[base + 5] = bfhi(v4.z);           \
  arr[base + 6] = bflo(v4.w); arr[base + 7] = bfhi(v4.w);

// ---------------------------------------------------------------------------
// K0: weight prep. gid<221184: f32->bf16 copy [in_proj 768x192][out_proj 192x384]
//     else: combined weight [512][384]: rows 0..383 dtw@x_proj fold,
//           384..415 = x_proj B/C rows, 416..511 zero.
// ---------------------------------------------------------------------------
__global__ __launch_bounds__(256) void prep_kernel(
    const float* __restrict__ w_in, const float* __restrict__ w_out,
    const float* __restrict__ xpw, const float* __restrict__ dtw,
    __hip_bfloat16* __restrict__ wbf, __hip_bfloat16* __restrict__ wcb) {
  int gid = blockIdx.x * 256 + threadIdx.x;   // < 417792
  if (gid < 221184) {
    float v = gid < 147456 ? w_in[gid] : w_out[gid - 147456];
    wbf[gid] = __float2bfloat16(v);
  } else {
    int e = gid - 221184;                      // < 196608
    int dd = e / 384, k = e % 384;
    float v = 0.f;
    if (dd < 384) {
#pragma unroll
      for (int j = 0; j < 12; ++j) v = fmaf(dtw[dd * 12 + j], xpw[j * 384 + k], v);
    } else if (dd < 416) {
      v = xpw[(dd - 372) * 384 + k];
    }
    wcb[e] = __float2bfloat16(v);
  }
}

// ---------------------------------------------------------------------------
// K1: [B,C,H,W] -> LayerNorm over C -> xn_bf16 [B*L, C]
// ---------------------------------------------------------------------------
__global__ __launch_bounds__(512) void ln_kernel(
    const float* __restrict__ x, const float* __restrict__ ln_w,
    const float* __restrict__ ln_b, __hip_bfloat16* __restrict__ xn) {
  __shared__ float xs[DIMC][WSP + 1];
  __shared__ float mu_s[WSP], rs_s[WSP];
  int bh = blockIdx.x;
  int b = bh >> 6, h = bh & 63;
  int tid = threadIdx.x;
  const float* xb = x + (size_t)b * DIMC * LSEQ + (size_t)h * WSP;
  for (int e = tid; e < DIMC * WSP; e += 512) {
    int c = e >> 6, w = e & 63;
    xs[c][w] = xb[(size_t)c * LSEQ + w];
  }
  __syncthreads();
  {
    int w = tid >> 3, p = tid & 7;
    float s = 0.f, s2 = 0.f;
#pragma unroll
    for (int i = 0; i < 24; ++i) {
      float v = xs[p * 24 + i][w];
      s += v; s2 = fmaf(v, v, s2);
    }
    s  += __shfl_xor(s, 1);  s2 += __shfl_xor(s2, 1);
    s  += __shfl_xor(s, 2);  s2 += __shfl_xor(s2, 2);
    s  += __shfl_xor(s, 4);  s2 += __shfl_xor(s2, 4);
    if (p == 0) {
      float mu = s * (1.f / DIMC);
      float var = s2 * (1.f / DIMC) - mu * mu;
      mu_s[w] = mu;
      rs_s[w] = rsqrtf(var + 1e-5f);
    }
  }
  __syncthreads();
  __hip_bfloat16* xo = xn + (size_t)(b * LSEQ + h * WSP) * DIMC;
  for (int e = tid; e < DIMC * WSP; e += 512) {
    int w = e / DIMC, c = e % DIMC;
    xo[(size_t)w * DIMC + c] =
        __float2bfloat16((xs[c][w] - mu_s[w]) * rs_s[w] * ln_w[c] + ln_b[c]);
  }
}

// ---------------------------------------------------------------------------
// bf16 MFMA GEMM, 2-phase pipelined K-loop (prefetch next tile during MFMA).
// C[M,N] = A[M,K] @ B[N,K]^T (row-major [dim][K] bf16).
// EPI 1: per-batch residual + f32 store [B,C,L], LDS-transposed coalesced.
// EPI 2: bf16 out, guard ncol<Nreal.
// EPI 4: fused x_proj+dt epilogue (pack dt+xm / B/C tile).
// ---------------------------------------------------------------------------
template<int WM, int WN, int FM, int FN, int EPI>
__global__ __launch_bounds__(256) void gemm_bf16(
    const ushortT* __restrict__ A, const ushortT* __restrict__ B,
    void* __restrict__ Cv, void* __restrict__ Cv2,
    const ushortT* __restrict__ xm_aux, const float* __restrict__ bias384,
    const float* __restrict__ xres, int K, int Nreal, int ldc) {
  constexpr int BM = WM * FM * 16, BN = WN * FN * 16;
  constexpr int AV = BM * 8 / 256;     // uint4 staging regs per thread (A)
  constexpr int BV = BN * 8 / 256;
  constexpr int SM_AB = (BM + BN) * 72 * 2;
  constexpr int SM_CT = (EPI == 1) ? BM * (BN + 4) * 4 : 0;
  constexpr int SMEM = SM_AB > SM_CT ? SM_AB : SM_CT;
  __shared__ __align__(16) char smem[SMEM];
  ushortT (*As)[72] = (ushortT(*)[72])smem;
  ushortT (*Bs)[72] = (ushortT(*)[72])(smem + (size_t)BM * 72 * 2);
  int bm = blockIdx.x * BM, bn = blockIdx.y * BN;
  int tid = threadIdx.x, lane = tid & 63, w = tid >> 6;
  int wm = w / WN, wn = w % WN;
  int lm = lane & 15, lk = lane >> 4;
  const ushortT* Bb = B;
  size_t zoff = 0;
  if constexpr (EPI == 1) {
    size_t zb = blockIdx.z;
    Bb = B + zb * (size_t)LSEQ * K;
    zoff = zb * (size_t)DIMC * LSEQ;
  }
  f32x4 acc[FM][FN];
#pragma unroll
  for (int mi = 0; mi < FM; ++mi)
#pragma unroll
    for (int ni = 0; ni < FN; ++ni) acc[mi][ni] = (f32x4){0.f, 0.f, 0.f, 0.f};

  uint4 areg[AV], breg[BV];
#pragma unroll
  for (int i = 0; i < AV; ++i) {
    int v = tid + i * 256, row = v >> 3, c8 = v & 7;
    areg[i] = *(const uint4*)(A + (size_t)(bm + row) * K + c8 * 8);
  }
#pragma unroll
  for (int i = 0; i < BV; ++i) {
    int v = tid + i * 256, row = v >> 3, c8 = v & 7;
    breg[i] = *(const uint4*)(Bb + (size_t)(bn + row) * K + c8 * 8);
  }

  for (int k0 = 0; k0 < K; k0 += 64) {
    __syncthreads();
#pragma unroll
    for (int i = 0; i < AV; ++i) {
      int v = tid + i * 256, row = v >> 3, c8 = v & 7;
      *(uint4*)&As[row][c8 * 8] = areg[i];
    }
#pragma unroll
    for (int i = 0; i < BV; ++i) {
      int v = tid + i * 256, row = v >> 3, c8 = v & 7;
      *(uint4*)&Bs[row][c8 * 8] = breg[i];
    }
    __syncthreads();
    if (k0 + 64 < K) {   // prefetch next tile; VMEM overlaps MFMA below
#pragma unroll
      for (int i = 0; i < AV; ++i) {
        int v = tid + i * 256, row = v >> 3, c8 = v & 7;
        areg[i] = *(const uint4*)(A + (size_t)(bm + row) * K + k0 + 64 + c8 * 8);
      }
#pragma unroll
      for (int i = 0; i < BV; ++i) {
        int v = tid + i * 256, row = v >> 3, c8 = v & 7;
        breg[i] = *(const uint4*)(Bb + (size_t)(bn + row) * K + k0 + 64 + c8 * 8);
      }
    }
#pragma unroll
    for (int ks = 0; ks < 2; ++ks) {
      short8 af[FM], bfr[FN];
#pragma unroll
      for (int mi = 0; mi < FM; ++mi)
        af[mi] = *(const short8*)&As[wm * FM * 16 + mi * 16 + lm][ks * 32 + lk * 8];
#pragma unroll
      for (int ni = 0; ni < FN; ++ni)
        bfr[ni] = *(const short8*)&Bs[wn * FN * 16 + ni * 16 + lm][ks * 32 + lk * 8];
#pragma unroll
      for (int mi = 0; mi < FM; ++mi)
#pragma unroll
        for (int ni = 0; ni < FN; ++ni)
          acc[mi][ni] = __builtin_amdgcn_mfma_f32_16x16x32_bf16(
              af[mi], bfr[ni], acc[mi][ni], 0, 0, 0);
    }
  }

  if constexpr (EPI == 1) {
    // stage C-tile in LDS (reuse As/Bs space), then fully-coalesced f32 I/O
    __syncthreads();
    float (*Ct)[BN + 4] = (float(*)[BN + 4])smem;
#pragma unroll
    for (int mi = 0; mi < FM; ++mi)
#pragma unroll
      for (int ni = 0; ni < FN; ++ni)
#pragma unroll
        for (int r = 0; r < 4; ++r)
          Ct[wm * FM * 16 + mi * 16 + lk * 4 + r][wn * FN * 16 + ni * 16 + lm] =
              acc[mi][ni][r];
    __syncthreads();
    float* Cout = (float*)Cv;
    for (int e = tid; e < BM * (BN / 4); e += 256) {
      int row = e / (BN / 4), q = e % (BN / 4);
      size_t gidx = zoff + (size_t)(bm + row) * LSEQ + bn + q * 4;
      float4 rv = *(const float4*)(xres + gidx);
      float4 o;
      o.x = Ct[row][q * 4 + 0] + rv.x;
      o.y = Ct[row][q * 4 + 1] + rv.y;
      o.z = Ct[row][q * 4 + 2] + rv.z;
      o.w = Ct[row][q * 4 + 3] + rv.w;
      *(float4*)(Cout + gidx) = o;
    }
  } else {
#pragma unroll
    for (int mi = 0; mi < FM; ++mi) {
#pragma unroll
      for (int ni = 0; ni < FN; ++ni) {
        int ncol = bn + wn * FN * 16 + ni * 16 + lm;
#pragma unroll
        for (int r = 0; r < 4; ++r) {
          int m = bm + wm * FM * 16 + mi * 16 + lk * 4 + r;
          if constexpr (EPI == 2) {
            if (ncol < Nreal)
              ((__hip_bfloat16*)Cv)[(size_t)m * ldc + ncol] =
                  __float2bfloat16(acc[mi][ni][r]);
          } else {  // EPI 4
            if (ncol < 384) {
              float dtr = acc[mi][ni][r] + bias384[ncol];
              float dt = dtr > 15.f ? dtr : __logf(1.f + __expf(dtr));
              float xmv = bf2f(xm_aux[(size_t)m * DINNER + ncol]);
              ((unsigned*)Cv)[(size_t)m * DINNER + ncol] = pkbf(dt, xmv);
            } else if (ncol < 416) {
              __hip_bfloat16 bv = __float2bfloat16(acc[mi][ni][r]);
              ((ushortT*)Cv2)[(size_t)m * 48 + 16 + (ncol - 384)] = *(ushortT*)&bv;
            }
          }
        }
      }
    }
  }
}

// ---------------------------------------------------------------------------
// K3: causal depthwise conv (k=4) + bias + SiLU, 8 channels per thread
// ---------------------------------------------------------------------------
__global__ __launch_bounds__(256) void conv_silu_kernel(
    const __hip_bfloat16* __restrict__ xz, const float* __restrict__ conv_w,
    const float* __restrict__ conv_b, __hip_bfloat16* __restrict__ xmh) {
  int g8 = blockIdx.x * 256 + threadIdx.x;      // < NTOK*384/8
  int d8 = g8 % 48;
  int tok = g8 / 48;
  int l = tok & (LSEQ - 1);
  int d0 = d8 * 8;
  const ushortT* base = (const ushortT*)xz + (size_t)tok * XZW + d0;
  uint4 r0, r1, r2, r3;
  r3 = *(const uint4*)(base);
  r2 = l >= 1 ? *(const uint4*)(base - XZW)     : (uint4){0, 0, 0, 0};
  r1 = l >= 2 ? *(const uint4*)(base - 2 * XZW) : (uint4){0, 0, 0, 0};
  r0 = l >= 3 ? *(const uint4*)(base - 3 * XZW) : (uint4){0, 0, 0, 0};
  float x0[8], x1[8], x2[8], x3[8];
  UNPK8(x0, 0, r0) UNPK8(x1, 0, r1) UNPK8(x2, 0, r2) UNPK8(x3, 0, r3)
  ushortT outv[8];
#pragma unroll
  for (int j = 0; j < 8; ++j) {
    const float4 w = *(const float4*)(conv_w + (d0 + j) * 4);
    float acc = conv_b[d0 + j];
    acc = fmaf(w.x, x0[j], acc);
    acc = fmaf(w.y, x1[j], acc);
    acc = fmaf(w.z, x2[j], acc);
    acc = fmaf(w.w, x3[j], acc);
    float s = acc / (1.f + __expf(-acc));
    __hip_bfloat16 sb = __float2bfloat16(s);
    outv[j] = *(ushortT*)&sb;
  }
  *(uint4*)((ushortT*)xmh + (size_t)tok * DINNER + d0) = *(uint4*)outv;
}

// ---------------------------------------------------------------------------
// K6a: chunk-local scan (LC=16): h_end from 0 + decay product -> packed u32
// ---------------------------------------------------------------------------
__global__ __launch_bounds__(384) void scan_part1(
    const unsigned* __restrict__ dxpk, const ushortT* __restrict__ dbc,
    const float* __restrict__ A_log, unsigned* __restrict__ hpk) {
  __shared__ ushortT dbc_s[16 * 48];
  int d = threadIdx.x, c = blockIdx.x, b = blockIdx.y;
  size_t rowbase = (size_t)b * LSEQ + (size_t)c * LC4;
  if (d < 96) {
    int row = d / 6, q = d % 6;
    ((uint4*)dbc_s)[d] = ((const uint4*)(dbc + (rowbase + row) * 48))[q];
  }
  float Ac2[16];
#pragma unroll
  for (int q = 0; q < 4; ++q) {
    float4 t4 = *(const float4*)(A_log + d * 16 + q * 4);
    Ac2[q * 4 + 0] = -__expf(t4.x) * 1.44269504f;
    Ac2[q * 4 + 1] = -__expf(t4.y) * 1.44269504f;
    Ac2[q * 4 + 2] = -__expf(t4.z) * 1.44269504f;
    Ac2[q * 4 + 3] = -__expf(t4.w) * 1.44269504f;
  }
  float h[16];
#pragma unroll
  for (int n = 0; n < 16; ++n) h[n] = 0.f;
  float sdt = 0.f;
  const unsigned* pkp = dxpk + rowbase * DINNER + d;
  __syncthreads();
#pragma unroll
  for (int t0 = 0; t0 < 16; t0 += 4) {
    unsigned pk[4];
#pragma unroll
    for (int j = 0; j < 4; ++j) pk[j] = pkp[(t0 + j) * DINNER];
#pragma unroll
    for (int j = 0; j < 4; ++j) {
      int t = t0 + j;
      float dtt = bflo(pk[j]), xmv = bfhi(pk[j]);
      sdt += dtt;
      float dx = dtt * xmv;
      const char* bb = (const char*)dbc_s + t * 96;
      uint4 B0 = *(const uint4*)(bb + 32);
      uint4 B1 = *(const uint4*)(bb + 48);
      float Bv[16];
      UNPK8(Bv, 0, B0)
      UNPK8(Bv, 8, B1)
#pragma unroll
      for (int n = 0; n < 16; ++n) {
        float a = __builtin_amdgcn_exp2f(dtt * Ac2[n]);
        h[n] = fmaf(h[n], a, dx * Bv[n]);
      }
    }
  }
  unsigned up[16];
#pragma unroll
  for (int n = 0; n < 16; ++n)
    up[n] = pkbf(h[n], __builtin_amdgcn_exp2f(Ac2[n] * sdt));
  uint4* hp4 = (uint4*)(hpk + (((size_t)b * NCH4 + c) * DINNER + d) * 16);
#pragma unroll
  for (int q = 0; q < 4; ++q) hp4[q] = *(uint4*)&up[q * 4];
}

// ---------------------------------------------------------------------------
// K6b: sequential chunk-boundary propagation
// ---------------------------------------------------------------------------
__global__ __launch_bounds__(256) void scan_part2(
    const unsigned* __restrict__ hpk, ushortT* __restrict__ hinb) {
  int e = blockIdx.x * 256 + threadIdx.x;   // [0, 6144)
  int b = blockIdx.y;
  float H = 0.f;
  size_t base = (size_t)b * NCH4 * (DINNER * DSTATE) + e;
#pragma unroll 16
  for (int c = 0; c < NCH4; ++c) {
    size_t idx = base + (size_t)c * (DINNER * DSTATE);
    unsigned w = hpk[idx];
    __hip_bfloat16 hb = __float2bfloat16(H);
    hinb[idx] = *(ushortT*)&hb;
    H = fmaf(bfhi(w), H, bflo(w));   // pa = hi, h_end = lo
  }
}

// ---------------------------------------------------------------------------
// K6c: seeded chunk scan -> y (in-lane C-dot) + D-skip + SiLU gate -> ybuf
// ---------------------------------------------------------------------------
__global__ __launch_bounds__(384) void scan_part3(
    const unsigned* __restrict__ dxpk, const ushortT* __restrict__ dbc,
    const __hip_bfloat16* __restrict__ xz, const float* __restrict__ A_log,
    const float* __restrict__ Dvec, const ushortT* __restrict__ hinb,
    __hip_bfloat16* __restrict__ ybuf) {
  __shared__ ushortT dbc_s[16 * 48];
  int d = threadIdx.x, c = blockIdx.x, b = blockIdx.y;
  size_t rowbase = (size_t)b * LSEQ + (size_t)c * LC4;
  if (d < 96) {
    int row = d / 6, q = d % 6;
    ((uint4*)dbc_s)[d] = ((const uint4*)(dbc + (rowbase + row) * 48))[q];
  }
  float Ac2[16];
#pragma unroll
  for (int q = 0; q < 4; ++q) {
    float4 t4 = *(const float4*)(A_log + d * 16 + q * 4);
    Ac2[q * 4 + 0] = -__expf(t4.x) * 1.44269504f;
    Ac2[q * 4 + 1] = -__expf(t4.y) * 1.44269504f;
    Ac2[q * 4 + 2] = -__expf(t4.z) * 1.44269504f;
    Ac2[q * 4 + 3] = -__expf(t4.w) * 1.44269504f;
  }
  float h[16];
  {
    const uint4* hp = (const uint4*)(hinb + (((size_t)b * NCH4 + c) * DINNER + d) * 16);
    uint4 h0 = hp[0], h1 = hp[1];
    UNPK8(h, 0, h0)
    UNPK8(h, 8, h1)
  }
  float Dd = Dvec[d];
  const unsigned* pkp = dxpk + rowbase * DINNER + d;
  const ushortT* zp = (const ushortT*)xz + rowbase * XZW + DINNER + d;
  __hip_bfloat16* yp = ybuf + rowbase * DINNER + d;
  __syncthreads();
#pragma unroll
  for (int t0 = 0; t0 < 16; t0 += 4) {
    unsigned pk[4];
    ushortT zv4[4];
#pragma unroll
    for (int j = 0; j < 4; ++j) {
      pk[j] = pkp[(t0 + j) * DINNER];
      zv4[j] = zp[(t0 + j) * XZW];
    }
#pragma unroll
    for (int j = 0; j < 4; ++j) {
      int t = t0 + j;
      float dtt = bflo(pk[j]), xmv = bfhi(pk[j]);
      float dx = dtt * xmv;
      const char* bb = (const char*)dbc_s + t * 96;
      uint4 B0 = *(const uint4*)(bb + 32);
      uint4 B1 = *(const uint4*)(bb + 48);
      uint4 C0 = *(const uint4*)(bb + 64);
      uint4 C1 = *(const uint4*)(bb + 80);
      float Bv[16], Cw[16];
      UNPK8(Bv, 0, B0)
      UNPK8(Bv, 8, B1)
      UNPK8(Cw, 0, C0)
      UNPK8(Cw, 8, C1)
      float y0 = 0.f, y1 = 0.f, y2 = 0.f, y3 = 0.f;
#pragma unroll
      for (int n = 0; n < 16; n += 4) {
        float a0 = __builtin_amdgcn_exp2f(dtt * Ac2[n + 0]);
        float a1 = __builtin_amdgcn_exp2f(dtt * Ac2[n + 1]);
        float a2 = __builtin_amdgcn_exp2f(dtt * Ac2[n + 2]);
        float a3 = __builtin_amdgcn_exp2f(dtt * Ac2[n + 3]);
        h[n + 0] = fmaf(h[n + 0], a0, dx * Bv[n + 0]);
        h[n + 1] = fmaf(h[n + 1], a1, dx * Bv[n + 1]);
        h[n + 2] = fmaf(h[n + 2], a2, dx * Bv[n + 2]);
        h[n + 3] = fmaf(h[n + 3], a3, dx * Bv[n + 3]);
        y0 = fmaf(h[n + 0], Cw[n + 0], y0);
        y1 = fmaf(h[n + 1], Cw[n + 1], y1);
        y2 = fmaf(h[n + 2], Cw[n + 2], y2);
        y3 = fmaf(h[n + 3], Cw[n + 3], y3);
      }
      float yv = fmaf(xmv, Dd, (y0 + y1) + (y2 + y3));
      float zv = bf2f(zv4[j]);
      float gt = zv * __builtin_amdgcn_rcpf(
          1.f + __builtin_amdgcn_exp2f(zv * -1.44269504f));
      yp[(size_t)t * DINNER] = __float2bfloat16(yv * gt);
    }
  }
}

// ---------------------------------------------------------------------------
extern "C" void kernel_launch(void* const* d_in, const int* in_sizes, int n_in,
                              void* d_out, int out_size, void* d_ws, size_t ws_size,
                              hipStream_t stream) {
  const float* x        = (const float*)d_in[0];
  const float* ln_w     = (const float*)d_in[1];
  const float* ln_b     = (const float*)d_in[2];
  const float* in_proj  = (const float*)d_in[3];   // [768,192]
  const float* conv_w   = (const float*)d_in[4];   // [384,4]
  const float* conv_b   = (const float*)d_in[5];   // [384]
  const float* x_proj   = (const float*)d_in[6];   // [44,384]
  const float* dt_w     = (const float*)d_in[7];   // [384,12]
  const float* dt_b     = (const float*)d_in[8];   // [384]
  const float* A_log    = (const float*)d_in[9];   // [384,16]
  const float* Dvec     = (const float*)d_in[10];  // [384]
  const float* out_proj = (const float*)d_in[11];  // [192,384]
  float* out = (float*)d_out;

  // workspace layout (float units), ~122 MB
  float* ws = (float*)d_ws;
  __hip_bfloat16* xzb  = (__hip_bfloat16*)ws;                    // [16384][768] bf16
  __hip_bfloat16* xmh  = (__hip_bfloat16*)(ws + 6291456);        // [16384][384] bf16
  ushortT*        dbcb = (ushortT*)(ws + 9437184);               // [16384][48] bf16
  unsigned*       dxpk = (unsigned*)(ws + 9830400);              // [16384][384] u32 (dt,xm)
  unsigned*       hpk  = (unsigned*)(ws + 16121856);             // [4][256][384][16] u32
  ushortT*        hinb = (ushortT*)(ws + 22413312);              // same shape bf16
  __hip_bfloat16* ybuf = (__hip_bfloat16*)(ws + 25559040);       // [16384][384] bf16
  __hip_bfloat16* xnbf = (__hip_bfloat16*)(ws + 28704768);       // [16384][192] bf16
  __hip_bfloat16* wbf  = (__hip_bfloat16*)(ws + 30277632);       // 221184 bf16
  __hip_bfloat16* wcb  = (__hip_bfloat16*)(ws + 30388224);       // 512*384 bf16

  const ushortT* win  = (const ushortT*)wbf;             // [768][192]
  const ushortT* wout = (const ushortT*)(wbf + 147456);  // [192][384]

  prep_kernel<<<1632, 256, 0, stream>>>(in_proj, out_proj, x_proj, dt_w, wbf, wcb);

  ln_kernel<<<BSZ * HSP, 512, 0, stream>>>(x, ln_w, ln_b, xnbf);

  // in_proj: [16384,192] x [768,192]^T -> xzb bf16 [16384,768]  (BM=128,BN=128)
  gemm_bf16<2, 2, 4, 4, 2><<<dim3(NTOK / 128, XZW / 128), 256, 0, stream>>>(
      (const ushortT*)xnbf, win, xzb, nullptr, nullptr, nullptr, nullptr,
      DIMC, XZW, XZW);

  conv_silu_kernel<<<(NTOK * DINNER / 8) / 256, 256, 0, stream>>>(
      xzb, conv_w, conv_b, xmh);

  // fused x_proj + dt_proj + softplus + pack: [16384,384] x [512,384]^T
  gemm_bf16<2, 2, 4, 4, 4><<<dim3(NTOK / 128, NXP / 128), 256, 0, stream>>>(
      (const ushortT*)xmh, (const ushortT*)wcb, dxpk, dbcb,
      (const ushortT*)xmh, dt_b, nullptr, DINNER, NXP, 0);

  scan_part1<<<dim3(NCH4, BSZ), 384, 0, stream>>>(dxpk, dbcb, A_log, hpk);
  scan_part2<<<dim3(DINNER * DSTATE / 256, BSZ), 256, 0, stream>>>(hpk, hinb);
  scan_part3<<<dim3(NCH4, BSZ), 384, 0, stream>>>(
      dxpk, dbcb, xzb, A_log, Dvec, hinb, ybuf);

  // out_proj: A=w_out[192][384], B=ybuf[b][4096][384] -> out[b][192][4096] + residual
  gemm_bf16<2, 2, 2, 4, 1><<<dim3(DIMC / 64, LSEQ / 128, BSZ), 256, 0, stream>>>(
      wout, (const ushortT*)ybuf, out, nullptr, nullptr, nullptr, x,
      DINNER, LSEQ, LSEQ);
}

// Round 9
// 173.253 us; speedup vs baseline: 1.2425x; 1.2425x over previous
//
#include <hip/hip_runtime.h>
#include <hip/hip_bf16.h>
#include <cstdint>
#include <cmath>

#define DIMC   192
#define DSTATE 16
#define DCONV  4
#define DINNER 384
#define DTRANK 12
#define BSZ    4
#define HSP    64
#define WSP    64
#define LSEQ   4096
#define NTOK   (BSZ*LSEQ)            // 16384
#define XZW    (2*DINNER)            // 768
#define LC4    16                    // scan chunk length
#define NCH4   (LSEQ/LC4)            // 256 chunks per batch
#define NXP    448                   // padded fused x_proj+dt output width

typedef unsigned short ushortT;
using short8 = __attribute__((ext_vector_type(8))) short;
using f32x4  = __attribute__((ext_vector_type(4))) float;

__device__ __forceinline__ float bflo(unsigned u) { return __uint_as_float(u << 16); }
__device__ __forceinline__ float bfhi(unsigned u) { return __uint_as_float(u & 0xffff0000u); }
__device__ __forceinline__ float bf2f(ushortT u) { return __uint_as_float(((unsigned)u) << 16); }
__device__ __forceinline__ unsigned pkbf(float lo, float hi) {
  __hip_bfloat16 l = __float2bfloat16(lo), h = __float2bfloat16(hi);
  return (unsigned)*(ushortT*)&l | ((unsigned)*(ushortT*)&h << 16);
}
#define UNPK8(arr, base, v4)                                        \
  arr[base + 0] = bflo(v4.x); arr[base + 1] = bfhi(v4.x);           \
  arr[base + 2] = bflo(v4.y); arr[base + 3] = bfhi(v4.y);           \
  arr[base + 4] = bflo(v4.z); arr[base + 5] = bfhi(v4.z);           \
  arr[base + 6] = bflo(v4.w); arr[base + 7] = bfhi(v4.w);

// ---------------------------------------------------------------------------
// K0: weight prep. gid<221184: f32->bf16 copy [in_proj 768x192][out_proj 192x384]
//     else: combined weight [448][384]: rows 0..383 dtw@x_proj fold,
//           384..415 = x_proj B/C rows, 416..447 zero.
// ---------------------------------------------------------------------------
__global__ __launch_bounds__(256) void prep_kernel(
    const float* __restrict__ w_in, const float* __restrict__ w_out,
    const float* __restrict__ xpw, const float* __restrict__ dtw,
    __hip_bfloat16* __restrict__ wbf, __hip_bfloat16* __restrict__ wcb) {
  int gid = blockIdx.x * 256 + threadIdx.x;   // < 393216
  if (gid < 221184) {
    float v = gid < 147456 ? w_in[gid] : w_out[gid - 147456];
    wbf[gid] = __float2bfloat16(v);
  } else {
    int e = gid - 221184;                      // < 172032
    int dd = e / 384, k = e % 384;
    float v = 0.f;
    if (dd < 384) {
#pragma unroll
      for (int j = 0; j < 12; ++j) v = fmaf(dtw[dd * 12 + j], xpw[j * 384 + k], v);
    } else if (dd < 416) {
      v = xpw[(dd - 372) * 384 + k];
    }
    wcb[e] = __float2bfloat16(v);
  }
}

// ---------------------------------------------------------------------------
// K1: [B,C,H,W] -> LayerNorm over C -> xn_bf16 [B*L, C]
// ---------------------------------------------------------------------------
__global__ __launch_bounds__(512) void ln_kernel(
    const float* __restrict__ x, const float* __restrict__ ln_w,
    const float* __restrict__ ln_b, __hip_bfloat16* __restrict__ xn) {
  __shared__ float xs[DIMC][WSP + 1];
  __shared__ float mu_s[WSP], rs_s[WSP];
  int bh = blockIdx.x;
  int b = bh >> 6, h = bh & 63;
  int tid = threadIdx.x;
  const float* xb = x + (size_t)b * DIMC * LSEQ + (size_t)h * WSP;
  for (int e = tid; e < DIMC * WSP; e += 512) {
    int c = e >> 6, w = e & 63;
    xs[c][w] = xb[(size_t)c * LSEQ + w];
  }
  __syncthreads();
  {
    int w = tid >> 3, p = tid & 7;
    float s = 0.f, s2 = 0.f;
#pragma unroll
    for (int i = 0; i < 24; ++i) {
      float v = xs[p * 24 + i][w];
      s += v; s2 = fmaf(v, v, s2);
    }
    s  += __shfl_xor(s, 1);  s2 += __shfl_xor(s2, 1);
    s  += __shfl_xor(s, 2);  s2 += __shfl_xor(s2, 2);
    s  += __shfl_xor(s, 4);  s2 += __shfl_xor(s2, 4);
    if (p == 0) {
      float mu = s * (1.f / DIMC);
      float var = s2 * (1.f / DIMC) - mu * mu;
      mu_s[w] = mu;
      rs_s[w] = rsqrtf(var + 1e-5f);
    }
  }
  __syncthreads();
  __hip_bfloat16* xo = xn + (size_t)(b * LSEQ + h * WSP) * DIMC;
  for (int e = tid; e < DIMC * WSP; e += 512) {
    int w = e / DIMC, c = e % DIMC;
    xo[(size_t)w * DIMC + c] =
        __float2bfloat16((xs[c][w] - mu_s[w]) * rs_s[w] * ln_w[c] + ln_b[c]);
  }
}

// ---------------------------------------------------------------------------
// bf16 MFMA GEMM (round-7 direct-staging structure).
// C[M,N] = A[M,K] @ B[N,K]^T (row-major [dim][K] bf16).
// EPI 1: per-batch residual + f32 store [B,C,L], LDS-staged coalesced epilogue.
// EPI 2: bf16 out, guard ncol<Nreal.
// EPI 4: fused x_proj+dt epilogue (pack dt+xm / B/C tile).
// ---------------------------------------------------------------------------
template<int WM, int WN, int FM, int FN, int EPI>
__global__ __launch_bounds__(256) void gemm_bf16(
    const ushortT* __restrict__ A, const ushortT* __restrict__ B,
    void* __restrict__ Cv, void* __restrict__ Cv2,
    const ushortT* __restrict__ xm_aux, const float* __restrict__ bias384,
    const float* __restrict__ xres, int K, int Nreal, int ldc) {
  constexpr int BM = WM * FM * 16, BN = WN * FN * 16;
  __shared__ ushortT As[BM][72];
  __shared__ ushortT Bs[BN][72];
  __shared__ float Ct[(EPI == 1) ? (BM * (BN + 4)) : 1];
  int bm = blockIdx.x * BM, bn = blockIdx.y * BN;
  int tid = threadIdx.x, lane = tid & 63, w = tid >> 6;
  int wm = w / WN, wn = w % WN;
  int lm = lane & 15, lk = lane >> 4;
  const ushortT* Bb = B;
  size_t zoff = 0;
  if constexpr (EPI == 1) {
    size_t zb = blockIdx.z;
    Bb = B + zb * (size_t)LSEQ * K;
    zoff = zb * (size_t)DIMC * LSEQ;
  }
  f32x4 acc[FM][FN];
#pragma unroll
  for (int mi = 0; mi < FM; ++mi)
#pragma unroll
    for (int ni = 0; ni < FN; ++ni) acc[mi][ni] = (f32x4){0.f, 0.f, 0.f, 0.f};

  for (int k0 = 0; k0 < K; k0 += 64) {
    __syncthreads();
    for (int v = tid; v < BM * 8; v += 256) {
      int row = v >> 3, c8 = v & 7;
      *(uint4*)&As[row][c8 * 8] =
          *(const uint4*)(A + (size_t)(bm + row) * K + k0 + c8 * 8);
    }
    for (int v = tid; v < BN * 8; v += 256) {
      int row = v >> 3, c8 = v & 7;
      *(uint4*)&Bs[row][c8 * 8] =
          *(const uint4*)(Bb + (size_t)(bn + row) * K + k0 + c8 * 8);
    }
    __syncthreads();
#pragma unroll
    for (int ks = 0; ks < 2; ++ks) {
      short8 af[FM], bfr[FN];
#pragma unroll
      for (int mi = 0; mi < FM; ++mi)
        af[mi] = *(const short8*)&As[wm * FM * 16 + mi * 16 + lm][ks * 32 + lk * 8];
#pragma unroll
      for (int ni = 0; ni < FN; ++ni)
        bfr[ni] = *(const short8*)&Bs[wn * FN * 16 + ni * 16 + lm][ks * 32 + lk * 8];
#pragma unroll
      for (int mi = 0; mi < FM; ++mi)
#pragma unroll
        for (int ni = 0; ni < FN; ++ni)
          acc[mi][ni] = __builtin_amdgcn_mfma_f32_16x16x32_bf16(
              af[mi], bfr[ni], acc[mi][ni], 0, 0, 0);
    }
  }

  if constexpr (EPI == 1) {
    // stage C-tile in LDS, then fully-coalesced float4 residual+store
    float (*CtA)[BN + 4] = (float(*)[BN + 4])Ct;
#pragma unroll
    for (int mi = 0; mi < FM; ++mi)
#pragma unroll
      for (int ni = 0; ni < FN; ++ni)
#pragma unroll
        for (int r = 0; r < 4; ++r)
          CtA[wm * FM * 16 + mi * 16 + lk * 4 + r][wn * FN * 16 + ni * 16 + lm] =
              acc[mi][ni][r];
    __syncthreads();
    float* Cout = (float*)Cv;
    for (int e = tid; e < BM * (BN / 4); e += 256) {
      int row = e / (BN / 4), q = e % (BN / 4);
      size_t gidx = zoff + (size_t)(bm + row) * LSEQ + bn + q * 4;
      float4 rv = *(const float4*)(xres + gidx);
      float4 o;
      o.x = CtA[row][q * 4 + 0] + rv.x;
      o.y = CtA[row][q * 4 + 1] + rv.y;
      o.z = CtA[row][q * 4 + 2] + rv.z;
      o.w = CtA[row][q * 4 + 3] + rv.w;
      *(float4*)(Cout + gidx) = o;
    }
  } else {
#pragma unroll
    for (int mi = 0; mi < FM; ++mi) {
#pragma unroll
      for (int ni = 0; ni < FN; ++ni) {
        int ncol = bn + wn * FN * 16 + ni * 16 + lm;
#pragma unroll
        for (int r = 0; r < 4; ++r) {
          int m = bm + wm * FM * 16 + mi * 16 + lk * 4 + r;
          if constexpr (EPI == 2) {
            if (ncol < Nreal)
              ((__hip_bfloat16*)Cv)[(size_t)m * ldc + ncol] =
                  __float2bfloat16(acc[mi][ni][r]);
          } else {  // EPI 4
            if (ncol < 384) {
              float dtr = acc[mi][ni][r] + bias384[ncol];
              float dt = dtr > 15.f ? dtr : __logf(1.f + __expf(dtr));
              float xmv = bf2f(xm_aux[(size_t)m * DINNER + ncol]);
              ((unsigned*)Cv)[(size_t)m * DINNER + ncol] = pkbf(dt, xmv);
            } else if (ncol < 416) {
              __hip_bfloat16 bv = __float2bfloat16(acc[mi][ni][r]);
              ((ushortT*)Cv2)[(size_t)m * 48 + 16 + (ncol - 384)] = *(ushortT*)&bv;
            }
          }
        }
      }
    }
  }
}

// ---------------------------------------------------------------------------
// K3: causal depthwise conv (k=4) + bias + SiLU, 8 channels per thread
// ---------------------------------------------------------------------------
__global__ __launch_bounds__(256) void conv_silu_kernel(
    const __hip_bfloat16* __restrict__ xz, const float* __restrict__ conv_w,
    const float* __restrict__ conv_b, __hip_bfloat16* __restrict__ xmh) {
  int g8 = blockIdx.x * 256 + threadIdx.x;      // < NTOK*384/8
  int d8 = g8 % 48;
  int tok = g8 / 48;
  int l = tok & (LSEQ - 1);
  int d0 = d8 * 8;
  const ushortT* base = (const ushortT*)xz + (size_t)tok * XZW + d0;
  uint4 r0, r1, r2, r3;
  r3 = *(const uint4*)(base);
  r2 = l >= 1 ? *(const uint4*)(base - XZW)     : (uint4){0, 0, 0, 0};
  r1 = l >= 2 ? *(const uint4*)(base - 2 * XZW) : (uint4){0, 0, 0, 0};
  r0 = l >= 3 ? *(const uint4*)(base - 3 * XZW) : (uint4){0, 0, 0, 0};
  float x0[8], x1[8], x2[8], x3[8];
  UNPK8(x0, 0, r0) UNPK8(x1, 0, r1) UNPK8(x2, 0, r2) UNPK8(x3, 0, r3)
  ushortT outv[8];
#pragma unroll
  for (int j = 0; j < 8; ++j) {
    const float4 w = *(const float4*)(conv_w + (d0 + j) * 4);
    float acc = conv_b[d0 + j];
    acc = fmaf(w.x, x0[j], acc);
    acc = fmaf(w.y, x1[j], acc);
    acc = fmaf(w.z, x2[j], acc);
    acc = fmaf(w.w, x3[j], acc);
    float s = acc / (1.f + __expf(-acc));
    __hip_bfloat16 sb = __float2bfloat16(s);
    outv[j] = *(ushortT*)&sb;
  }
  *(uint4*)((ushortT*)xmh + (size_t)tok * DINNER + d0) = *(uint4*)outv;
}

// ---------------------------------------------------------------------------
// K6a: chunk-local scan (LC=16): h_end from 0 + decay product -> packed u32
// ---------------------------------------------------------------------------
__global__ __launch_bounds__(384) void scan_part1(
    const unsigned* __restrict__ dxpk, const ushortT* __restrict__ dbc,
    const float* __restrict__ A_log, unsigned* __restrict__ hpk) {
  __shared__ ushortT dbc_s[16 * 48];
  int d = threadIdx.x, c = blockIdx.x, b = blockIdx.y;
  size_t rowbase = (size_t)b * LSEQ + (size_t)c * LC4;
  if (d < 96) {
    int row = d / 6, q = d % 6;
    ((uint4*)dbc_s)[d] = ((const uint4*)(dbc + (rowbase + row) * 48))[q];
  }
  float Ac2[16];
#pragma unroll
  for (int q = 0; q < 4; ++q) {
    float4 t4 = *(const float4*)(A_log + d * 16 + q * 4);
    Ac2[q * 4 + 0] = -__expf(t4.x) * 1.44269504f;
    Ac2[q * 4 + 1] = -__expf(t4.y) * 1.44269504f;
    Ac2[q * 4 + 2] = -__expf(t4.z) * 1.44269504f;
    Ac2[q * 4 + 3] = -__expf(t4.w) * 1.44269504f;
  }
  float h[16];
#pragma unroll
  for (int n = 0; n < 16; ++n) h[n] = 0.f;
  float sdt = 0.f;
  const unsigned* pkp = dxpk + rowbase * DINNER + d;
  __syncthreads();
#pragma unroll
  for (int t0 = 0; t0 < 16; t0 += 4) {
    unsigned pk[4];
#pragma unroll
    for (int j = 0; j < 4; ++j) pk[j] = pkp[(t0 + j) * DINNER];
#pragma unroll
    for (int j = 0; j < 4; ++j) {
      int t = t0 + j;
      float dtt = bflo(pk[j]), xmv = bfhi(pk[j]);
      sdt += dtt;
      float dx = dtt * xmv;
      const char* bb = (const char*)dbc_s + t * 96;
      uint4 B0 = *(const uint4*)(bb + 32);
      uint4 B1 = *(const uint4*)(bb + 48);
      float Bv[16];
      UNPK8(Bv, 0, B0)
      UNPK8(Bv, 8, B1)
#pragma unroll
      for (int n = 0; n < 16; ++n) {
        float a = __builtin_amdgcn_exp2f(dtt * Ac2[n]);
        h[n] = fmaf(h[n], a, dx * Bv[n]);
      }
    }
  }
  unsigned up[16];
#pragma unroll
  for (int n = 0; n < 16; ++n)
    up[n] = pkbf(h[n], __builtin_amdgcn_exp2f(Ac2[n] * sdt));
  uint4* hp4 = (uint4*)(hpk + (((size_t)b * NCH4 + c) * DINNER + d) * 16);
#pragma unroll
  for (int q = 0; q < 4; ++q) hp4[q] = *(uint4*)&up[q * 4];
}

// ---------------------------------------------------------------------------
// K6b: sequential chunk-boundary propagation
// ---------------------------------------------------------------------------
__global__ __launch_bounds__(256) void scan_part2(
    const unsigned* __restrict__ hpk, ushortT* __restrict__ hinb) {
  int e = blockIdx.x * 256 + threadIdx.x;   // [0, 6144)
  int b = blockIdx.y;
  float H = 0.f;
  size_t base = (size_t)b * NCH4 * (DINNER * DSTATE) + e;
#pragma unroll 16
  for (int c = 0; c < NCH4; ++c) {
    size_t idx = base + (size_t)c * (DINNER * DSTATE);
    unsigned w = hpk[idx];
    __hip_bfloat16 hb = __float2bfloat16(H);
    hinb[idx] = *(ushortT*)&hb;
    H = fmaf(bfhi(w), H, bflo(w));   // pa = hi, h_end = lo
  }
}

// ---------------------------------------------------------------------------
// K6c: seeded chunk scan -> y (in-lane C-dot) + D-skip + SiLU gate -> ybuf
// ---------------------------------------------------------------------------
__global__ __launch_bounds__(384) void scan_part3(
    const unsigned* __restrict__ dxpk, const ushortT* __restrict__ dbc,
    const __hip_bfloat16* __restrict__ xz, const float* __restrict__ A_log,
    const float* __restrict__ Dvec, const ushortT* __restrict__ hinb,
    __hip_bfloat16* __restrict__ ybuf) {
  __shared__ ushortT dbc_s[16 * 48];
  int d = threadIdx.x, c = blockIdx.x, b = blockIdx.y;
  size_t rowbase = (size_t)b * LSEQ + (size_t)c * LC4;
  if (d < 96) {
    int row = d / 6, q = d % 6;
    ((uint4*)dbc_s)[d] = ((const uint4*)(dbc + (rowbase + row) * 48))[q];
  }
  float Ac2[16];
#pragma unroll
  for (int q = 0; q < 4; ++q) {
    float4 t4 = *(const float4*)(A_log + d * 16 + q * 4);
    Ac2[q * 4 + 0] = -__expf(t4.x) * 1.44269504f;
    Ac2[q * 4 + 1] = -__expf(t4.y) * 1.44269504f;
    Ac2[q * 4 + 2] = -__expf(t4.z) * 1.44269504f;
    Ac2[q * 4 + 3] = -__expf(t4.w) * 1.44269504f;
  }
  float h[16];
  {
    const uint4* hp = (const uint4*)(hinb + (((size_t)b * NCH4 + c) * DINNER + d) * 16);
    uint4 h0 = hp[0], h1 = hp[1];
    UNPK8(h, 0, h0)
    UNPK8(h, 8, h1)
  }
  float Dd = Dvec[d];
  const unsigned* pkp = dxpk + rowbase * DINNER + d;
  const ushortT* zp = (const ushortT*)xz + rowbase * XZW + DINNER + d;
  __hip_bfloat16* yp = ybuf + rowbase * DINNER + d;
  __syncthreads();
#pragma unroll
  for (int t0 = 0; t0 < 16; t0 += 4) {
    unsigned pk[4];
    ushortT zv4[4];
#pragma unroll
    for (int j = 0; j < 4; ++j) {
      pk[j] = pkp[(t0 + j) * DINNER];
      zv4[j] = zp[(t0 + j) * XZW];
    }
#pragma unroll
    for (int j = 0; j < 4; ++j) {
      int t = t0 + j;
      float dtt = bflo(pk[j]), xmv = bfhi(pk[j]);
      float dx = dtt * xmv;
      const char* bb = (const char*)dbc_s + t * 96;
      uint4 B0 = *(const uint4*)(bb + 32);
      uint4 B1 = *(const uint4*)(bb + 48);
      uint4 C0 = *(const uint4*)(bb + 64);
      uint4 C1 = *(const uint4*)(bb + 80);
      float Bv[16], Cw[16];
      UNPK8(Bv, 0, B0)
      UNPK8(Bv, 8, B1)
      UNPK8(Cw, 0, C0)
      UNPK8(Cw, 8, C1)
      float y0 = 0.f, y1 = 0.f, y2 = 0.f, y3 = 0.f;
#pragma unroll
      for (int n = 0; n < 16; n += 4) {
        float a0 = __builtin_amdgcn_exp2f(dtt * Ac2[n + 0]);
        float a1 = __builtin_amdgcn_exp2f(dtt * Ac2[n + 1]);
        float a2 = __builtin_amdgcn_exp2f(dtt * Ac2[n + 2]);
        float a3 = __builtin_amdgcn_exp2f(dtt * Ac2[n + 3]);
        h[n + 0] = fmaf(h[n + 0], a0, dx * Bv[n + 0]);
        h[n + 1] = fmaf(h[n + 1], a1, dx * Bv[n + 1]);
        h[n + 2] = fmaf(h[n + 2], a2, dx * Bv[n + 2]);
        h[n + 3] = fmaf(h[n + 3], a3, dx * Bv[n + 3]);
        y0 = fmaf(h[n + 0], Cw[n + 0], y0);
        y1 = fmaf(h[n + 1], Cw[n + 1], y1);
        y2 = fmaf(h[n + 2], Cw[n + 2], y2);
        y3 = fmaf(h[n + 3], Cw[n + 3], y3);
      }
      float yv = fmaf(xmv, Dd, (y0 + y1) + (y2 + y3));
      float zv = bf2f(zv4[j]);
      float gt = zv * __builtin_amdgcn_rcpf(
          1.f + __builtin_amdgcn_exp2f(zv * -1.44269504f));
      yp[(size_t)t * DINNER] = __float2bfloat16(yv * gt);
    }
  }
}

// ---------------------------------------------------------------------------
extern "C" void kernel_launch(void* const* d_in, const int* in_sizes, int n_in,
                              void* d_out, int out_size, void* d_ws, size_t ws_size,
                              hipStream_t stream) {
  const float* x        = (const float*)d_in[0];
  const float* ln_w     = (const float*)d_in[1];
  const float* ln_b     = (const float*)d_in[2];
  const float* in_proj  = (const float*)d_in[3];   // [768,192]
  const float* conv_w   = (const float*)d_in[4];   // [384,4]
  const float* conv_b   = (const float*)d_in[5];   // [384]
  const float* x_proj   = (const float*)d_in[6];   // [44,384]
  const float* dt_w     = (const float*)d_in[7];   // [384,12]
  const float* dt_b     = (const float*)d_in[8];   // [384]
  const float* A_log    = (const float*)d_in[9];   // [384,16]
  const float* Dvec     = (const float*)d_in[10];  // [384]
  const float* out_proj = (const float*)d_in[11];  // [192,384]
  float* out = (float*)d_out;

  // workspace layout (float units), ~122 MB
  float* ws = (float*)d_ws;
  __hip_bfloat16* xzb  = (__hip_bfloat16*)ws;                    // [16384][768] bf16
  __hip_bfloat16* xmh  = (__hip_bfloat16*)(ws + 6291456);        // [16384][384] bf16
  ushortT*        dbcb = (ushortT*)(ws + 9437184);               // [16384][48] bf16
  unsigned*       dxpk = (unsigned*)(ws + 9830400);              // [16384][384] u32 (dt,xm)
  unsigned*       hpk  = (unsigned*)(ws + 16121856);             // [4][256][384][16] u32
  ushortT*        hinb = (ushortT*)(ws + 22413312);              // same shape bf16
  __hip_bfloat16* ybuf = (__hip_bfloat16*)(ws + 25559040);       // [16384][384] bf16
  __hip_bfloat16* xnbf = (__hip_bfloat16*)(ws + 28704768);       // [16384][192] bf16
  __hip_bfloat16* wbf  = (__hip_bfloat16*)(ws + 30277632);       // 221184 bf16
  __hip_bfloat16* wcb  = (__hip_bfloat16*)(ws + 30388224);       // 448*384 bf16

  const ushortT* win  = (const ushortT*)wbf;             // [768][192]
  const ushortT* wout = (const ushortT*)(wbf + 147456);  // [192][384]

  prep_kernel<<<1536, 256, 0, stream>>>(in_proj, out_proj, x_proj, dt_w, wbf, wcb);

  ln_kernel<<<BSZ * HSP, 512, 0, stream>>>(x, ln_w, ln_b, xnbf);

  // in_proj: [16384,192] x [768,192]^T -> xzb bf16 [16384,768]  (BM=128,BN=128)
  gemm_bf16<2, 2, 4, 4, 2><<<dim3(NTOK / 128, XZW / 128), 256, 0, stream>>>(
      (const ushortT*)xnbf, win, xzb, nullptr, nullptr, nullptr, nullptr,
      DIMC, XZW, XZW);

  conv_silu_kernel<<<(NTOK * DINNER / 8) / 256, 256, 0, stream>>>(
      xzb, conv_w, conv_b, xmh);

  // fused x_proj + dt_proj + softplus + pack: [16384,384] x [448,384]^T
  gemm_bf16<2, 2, 4, 2, 4><<<dim3(NTOK / 128, NXP / 64), 256, 0, stream>>>(
      (const ushortT*)xmh, (const ushortT*)wcb, dxpk, dbcb,
      (const ushortT*)xmh, dt_b, nullptr, DINNER, NXP, 0);

  scan_part1<<<dim3(NCH4, BSZ), 384, 0, stream>>>(dxpk, dbcb, A_log, hpk);
  scan_part2<<<dim3(DINNER * DSTATE / 256, BSZ), 256, 0, stream>>>(hpk, hinb);
  scan_part3<<<dim3(NCH4, BSZ), 384, 0, stream>>>(
      dxpk, dbcb, xzb, A_log, Dvec, hinb, ybuf);

  // out_proj: A=w_out[192][384], B=ybuf[b][4096][384] -> out[b][192][4096] + residual
  gemm_bf16<2, 2, 2, 4, 1><<<dim3(DIMC / 64, LSEQ / 128, BSZ), 256, 0, stream>>>(
      wout, (const ushortT*)ybuf, out, nullptr, nullptr, nullptr, x,
      DINNER, LSEQ, LSEQ);
}

// Round 10
// 154.773 us; speedup vs baseline: 1.3909x; 1.1194x over previous
//
#include <hip/hip_runtime.h>
#include <hip/hip_bf16.h>
#include <cstdint>
#include <cmath>

#define DIMC   192
#define DSTATE 16
#define DCONV  4
#define DINNER 384
#define DTRANK 12
#define BSZ    4
#define HSP    64
#define WSP    64
#define LSEQ   4096
#define NTOK   (BSZ*LSEQ)            // 16384
#define XZW    (2*DINNER)            // 768
#define LC4    16                    // scan chunk length
#define NCH4   (LSEQ/LC4)            // 256 chunks per batch
#define NXP    448                   // padded fused x_proj+dt output width

typedef unsigned short ushortT;
using short8 = __attribute__((ext_vector_type(8))) short;
using f32x4  = __attribute__((ext_vector_type(4))) float;

typedef unsigned int u32_as1 __attribute__((address_space(1)));
typedef unsigned int u32_as3 __attribute__((address_space(3)));

// async global->LDS DMA, 16 B per lane (lane i writes ldsbase + 16*i)
__device__ __forceinline__ void gl_lds16(const ushortT* g, ushortT* l) {
  __builtin_amdgcn_global_load_lds((const u32_as1*)g, (u32_as3*)l, 16, 0, 0);
}

__device__ __forceinline__ float bflo(unsigned u) { return __uint_as_float(u << 16); }
__device__ __forceinline__ float bfhi(unsigned u) { return __uint_as_float(u & 0xffff0000u); }
__device__ __forceinline__ float bf2f(ushortT u) { return __uint_as_float(((unsigned)u) << 16); }
__device__ __forceinline__ unsigned pkbf(float lo, float hi) {
  __hip_bfloat16 l = __float2bfloat16(lo), h = __float2bfloat16(hi);
  return (unsigned)*(ushortT*)&l | ((unsigned)*(ushortT*)&h << 16);
}
#define UNPK8(arr, base, v4)                                        \
  arr[base + 0] = bflo(v4.x); arr[base + 1] = bfhi(v4.x);           \
  arr[base + 2] = bflo(v4.y); arr[base + 3] = bfhi(v4.y);           \
  arr[base + 4] = bflo(v4.z); arr[base + 5] = bfhi(v4.z);           \
  arr[base + 6] = bflo(v4.w); arr[base + 7] = bfhi(v4.w);

// ---------------------------------------------------------------------------
// K0: weight prep. gid<221184: f32->bf16 copy [in_proj 768x192][out_proj 192x384]
//     else: combined weight [448][384]: rows 0..383 dtw@x_proj fold,
//           384..415 = x_proj B/C rows, 416..447 zero.
// ---------------------------------------------------------------------------
__global__ __launch_bounds__(256) void prep_kernel(
    const float* __restrict__ w_in, const float* __restrict__ w_out,
    const float* __restrict__ xpw, const float* __restrict__ dtw,
    __hip_bfloat16* __restrict__ wbf, __hip_bfloat16* __restrict__ wcb) {
  int gid = blockIdx.x * 256 + threadIdx.x;   // < 393216
  if (gid < 221184) {
    float v = gid < 147456 ? w_in[gid] : w_out[gid - 147456];
    wbf[gid] = __float2bfloat16(v);
  } else {
    int e = gid - 221184;                      // < 172032
    int dd = e / 384, k = e % 384;
    float v = 0.f;
    if (dd < 384) {
#pragma unroll
      for (int j = 0; j < 12; ++j) v = fmaf(dtw[dd * 12 + j], xpw[j * 384 + k], v);
    } else if (dd < 416) {
      v = xpw[(dd - 372) * 384 + k];
    }
    wcb[e] = __float2bfloat16(v);
  }
}

// ---------------------------------------------------------------------------
// K1: [B,C,H,W] -> LayerNorm over C -> xn_bf16 [B*L, C]
// ---------------------------------------------------------------------------
__global__ __launch_bounds__(512) void ln_kernel(
    const float* __restrict__ x, const float* __restrict__ ln_w,
    const float* __restrict__ ln_b, __hip_bfloat16* __restrict__ xn) {
  __shared__ float xs[DIMC][WSP + 1];
  __shared__ float mu_s[WSP], rs_s[WSP];
  int bh = blockIdx.x;
  int b = bh >> 6, h = bh & 63;
  int tid = threadIdx.x;
  const float* xb = x + (size_t)b * DIMC * LSEQ + (size_t)h * WSP;
  for (int e = tid; e < DIMC * WSP; e += 512) {
    int c = e >> 6, w = e & 63;
    xs[c][w] = xb[(size_t)c * LSEQ + w];
  }
  __syncthreads();
  {
    int w = tid >> 3, p = tid & 7;
    float s = 0.f, s2 = 0.f;
#pragma unroll
    for (int i = 0; i < 24; ++i) {
      float v = xs[p * 24 + i][w];
      s += v; s2 = fmaf(v, v, s2);
    }
    s  += __shfl_xor(s, 1);  s2 += __shfl_xor(s2, 1);
    s  += __shfl_xor(s, 2);  s2 += __shfl_xor(s2, 2);
    s  += __shfl_xor(s, 4);  s2 += __shfl_xor(s2, 4);
    if (p == 0) {
      float mu = s * (1.f / DIMC);
      float var = s2 * (1.f / DIMC) - mu * mu;
      mu_s[w] = mu;
      rs_s[w] = rsqrtf(var + 1e-5f);
    }
  }
  __syncthreads();
  __hip_bfloat16* xo = xn + (size_t)(b * LSEQ + h * WSP) * DIMC;
  for (int e = tid; e < DIMC * WSP; e += 512) {
    int w = e / DIMC, c = e % DIMC;
    xo[(size_t)w * DIMC + c] =
        __float2bfloat16((xs[c][w] - mu_s[w]) * rs_s[w] * ln_w[c] + ln_b[c]);
  }
}

// ---------------------------------------------------------------------------
// bf16 MFMA GEMM with global_load_lds DMA staging + XOR-swizzled LDS.
// LDS tile rows are 64 ushorts (128 B), unpadded (DMA needs linear dest).
// Swizzle: 16B k-slot s of row r stored at physical slot s^(r&7); ds_read
// applies the same XOR -> bank-conflict-free (2 lanes/bank).
// C[M,N] = A[M,K] @ B[N,K]^T (row-major [dim][K] bf16).
// EPI 1: per-batch residual + f32 store [B,C,L], LDS-staged coalesced epilogue.
// EPI 2: bf16 out, guard ncol<Nreal.
// EPI 4: fused x_proj+dt epilogue (pack dt+xm / B/C tile).
// ---------------------------------------------------------------------------
template<int WM, int WN, int FM, int FN, int EPI>
__global__ __launch_bounds__(256) void gemm_bf16(
    const ushortT* __restrict__ A, const ushortT* __restrict__ B,
    void* __restrict__ Cv, void* __restrict__ Cv2,
    const ushortT* __restrict__ xm_aux, const float* __restrict__ bias384,
    const float* __restrict__ xres, int K, int Nreal, int ldc) {
  constexpr int BM = WM * FM * 16, BN = WN * FN * 16;
  __shared__ ushortT As[BM][64];
  __shared__ ushortT Bs[BN][64];
  __shared__ float Ct[(EPI == 1) ? (BM * (BN + 4)) : 1];
  int bm = blockIdx.x * BM, bn = blockIdx.y * BN;
  int tid = threadIdx.x, lane = tid & 63, w = tid >> 6;
  int wm = w / WN, wn = w % WN;
  int lm = lane & 15, lk = lane >> 4;
  int sub = lane >> 3, slot = lane & 7;      // 8 rows x 8 slots per DMA inst
  const ushortT* Bb = B;
  size_t zoff = 0;
  if constexpr (EPI == 1) {
    size_t zb = blockIdx.z;
    Bb = B + zb * (size_t)LSEQ * K;
    zoff = zb * (size_t)DIMC * LSEQ;
  }
  f32x4 acc[FM][FN];
#pragma unroll
  for (int mi = 0; mi < FM; ++mi)
#pragma unroll
    for (int ni = 0; ni < FN; ++ni) acc[mi][ni] = (f32x4){0.f, 0.f, 0.f, 0.f};

  for (int k0 = 0; k0 < K; k0 += 64) {
    __syncthreads();
    // A-tile: wave w stages rows [w*BM/4, (w+1)*BM/4), 8 rows per instruction
#pragma unroll
    for (int j = 0; j < BM / 32; ++j) {
      int row = w * (BM / 4) + j * 8;        // group base (row&7 == sub per lane)
      gl_lds16(A + (size_t)(bm + row + sub) * K + k0 + ((slot ^ sub) << 3),
               &As[row][0]);
    }
#pragma unroll
    for (int j = 0; j < BN / 32; ++j) {
      int row = w * (BN / 4) + j * 8;
      gl_lds16(Bb + (size_t)(bn + row + sub) * K + k0 + ((slot ^ sub) << 3),
               &Bs[row][0]);
    }
    __syncthreads();   // drains the LDS-DMA (vmcnt) before reads
#pragma unroll
    for (int ks = 0; ks < 2; ++ks) {
      short8 af[FM], bfr[FN];
#pragma unroll
      for (int mi = 0; mi < FM; ++mi) {
        int row = wm * FM * 16 + mi * 16 + lm;
        int col = (ks * 64 + lk * 16) ^ ((lm & 7) << 4);
        af[mi] = *(const short8*)((const char*)As + row * 128 + col);
      }
#pragma unroll
      for (int ni = 0; ni < FN; ++ni) {
        int row = wn * FN * 16 + ni * 16 + lm;
        int col = (ks * 64 + lk * 16) ^ ((lm & 7) << 4);
        bfr[ni] = *(const short8*)((const char*)Bs + row * 128 + col);
      }
#pragma unroll
      for (int mi = 0; mi < FM; ++mi)
#pragma unroll
        for (int ni = 0; ni < FN; ++ni)
          acc[mi][ni] = __builtin_amdgcn_mfma_f32_16x16x32_bf16(
              af[mi], bfr[ni], acc[mi][ni], 0, 0, 0);
    }
  }

  if constexpr (EPI == 1) {
    // stage C-tile in LDS, then fully-coalesced float4 residual+store
    __syncthreads();
    float (*CtA)[BN + 4] = (float(*)[BN + 4])Ct;
#pragma unroll
    for (int mi = 0; mi < FM; ++mi)
#pragma unroll
      for (int ni = 0; ni < FN; ++ni)
#pragma unroll
        for (int r = 0; r < 4; ++r)
          CtA[wm * FM * 16 + mi * 16 + lk * 4 + r][wn * FN * 16 + ni * 16 + lm] =
              acc[mi][ni][r];
    __syncthreads();
    float* Cout = (float*)Cv;
    for (int e = tid; e < BM * (BN / 4); e += 256) {
      int row = e / (BN / 4), q = e % (BN / 4);
      size_t gidx = zoff + (size_t)(bm + row) * LSEQ + bn + q * 4;
      float4 rv = *(const float4*)(xres + gidx);
      float4 o;
      o.x = CtA[row][q * 4 + 0] + rv.x;
      o.y = CtA[row][q * 4 + 1] + rv.y;
      o.z = CtA[row][q * 4 + 2] + rv.z;
      o.w = CtA[row][q * 4 + 3] + rv.w;
      *(float4*)(Cout + gidx) = o;
    }
  } else {
#pragma unroll
    for (int mi = 0; mi < FM; ++mi) {
#pragma unroll
      for (int ni = 0; ni < FN; ++ni) {
        int ncol = bn + wn * FN * 16 + ni * 16 + lm;
#pragma unroll
        for (int r = 0; r < 4; ++r) {
          int m = bm + wm * FM * 16 + mi * 16 + lk * 4 + r;
          if constexpr (EPI == 2) {
            if (ncol < Nreal)
              ((__hip_bfloat16*)Cv)[(size_t)m * ldc + ncol] =
                  __float2bfloat16(acc[mi][ni][r]);
          } else {  // EPI 4
            if (ncol < 384) {
              float dtr = acc[mi][ni][r] + bias384[ncol];
              float dt = dtr > 15.f ? dtr : __logf(1.f + __expf(dtr));
              float xmv = bf2f(xm_aux[(size_t)m * DINNER + ncol]);
              ((unsigned*)Cv)[(size_t)m * DINNER + ncol] = pkbf(dt, xmv);
            } else if (ncol < 416) {
              __hip_bfloat16 bv = __float2bfloat16(acc[mi][ni][r]);
              ((ushortT*)Cv2)[(size_t)m * 48 + 16 + (ncol - 384)] = *(ushortT*)&bv;
            }
          }
        }
      }
    }
  }
}

// ---------------------------------------------------------------------------
// K3: causal depthwise conv (k=4) + bias + SiLU, 8 channels per thread
// ---------------------------------------------------------------------------
__global__ __launch_bounds__(256) void conv_silu_kernel(
    const __hip_bfloat16* __restrict__ xz, const float* __restrict__ conv_w,
    const float* __restrict__ conv_b, __hip_bfloat16* __restrict__ xmh) {
  int g8 = blockIdx.x * 256 + threadIdx.x;      // < NTOK*384/8
  int d8 = g8 % 48;
  int tok = g8 / 48;
  int l = tok & (LSEQ - 1);
  int d0 = d8 * 8;
  const ushortT* base = (const ushortT*)xz + (size_t)tok * XZW + d0;
  uint4 r0, r1, r2, r3;
  r3 = *(const uint4*)(base);
  r2 = l >= 1 ? *(const uint4*)(base - XZW)     : (uint4){0, 0, 0, 0};
  r1 = l >= 2 ? *(const uint4*)(base - 2 * XZW) : (uint4){0, 0, 0, 0};
  r0 = l >= 3 ? *(const uint4*)(base - 3 * XZW) : (uint4){0, 0, 0, 0};
  float x0[8], x1[8], x2[8], x3[8];
  UNPK8(x0, 0, r0) UNPK8(x1, 0, r1) UNPK8(x2, 0, r2) UNPK8(x3, 0, r3)
  ushortT outv[8];
#pragma unroll
  for (int j = 0; j < 8; ++j) {
    const float4 w = *(const float4*)(conv_w + (d0 + j) * 4);
    float acc = conv_b[d0 + j];
    acc = fmaf(w.x, x0[j], acc);
    acc = fmaf(w.y, x1[j], acc);
    acc = fmaf(w.z, x2[j], acc);
    acc = fmaf(w.w, x3[j], acc);
    float s = acc / (1.f + __expf(-acc));
    __hip_bfloat16 sb = __float2bfloat16(s);
    outv[j] = *(ushortT*)&sb;
  }
  *(uint4*)((ushortT*)xmh + (size_t)tok * DINNER + d0) = *(uint4*)outv;
}

// ---------------------------------------------------------------------------
// K6a: chunk-local scan (LC=16): h_end from 0 + decay product -> packed u32
// ---------------------------------------------------------------------------
__global__ __launch_bounds__(384) void scan_part1(
    const unsigned* __restrict__ dxpk, const ushortT* __restrict__ dbc,
    const float* __restrict__ A_log, unsigned* __restrict__ hpk) {
  __shared__ ushortT dbc_s[16 * 48];
  int d = threadIdx.x, c = blockIdx.x, b = blockIdx.y;
  size_t rowbase = (size_t)b * LSEQ + (size_t)c * LC4;
  if (d < 96) {
    int row = d / 6, q = d % 6;
    ((uint4*)dbc_s)[d] = ((const uint4*)(dbc + (rowbase + row) * 48))[q];
  }
  float Ac2[16];
#pragma unroll
  for (int q = 0; q < 4; ++q) {
    float4 t4 = *(const float4*)(A_log + d * 16 + q * 4);
    Ac2[q * 4 + 0] = -__expf(t4.x) * 1.44269504f;
    Ac2[q * 4 + 1] = -__expf(t4.y) * 1.44269504f;
    Ac2[q * 4 + 2] = -__expf(t4.z) * 1.44269504f;
    Ac2[q * 4 + 3] = -__expf(t4.w) * 1.44269504f;
  }
  float h[16];
#pragma unroll
  for (int n = 0; n < 16; ++n) h[n] = 0.f;
  float sdt = 0.f;
  const unsigned* pkp = dxpk + rowbase * DINNER + d;
  __syncthreads();
#pragma unroll
  for (int t0 = 0; t0 < 16; t0 += 4) {
    unsigned pk[4];
#pragma unroll
    for (int j = 0; j < 4; ++j) pk[j] = pkp[(t0 + j) * DINNER];
#pragma unroll
    for (int j = 0; j < 4; ++j) {
      int t = t0 + j;
      float dtt = bflo(pk[j]), xmv = bfhi(pk[j]);
      sdt += dtt;
      float dx = dtt * xmv;
      const char* bb = (const char*)dbc_s + t * 96;
      uint4 B0 = *(const uint4*)(bb + 32);
      uint4 B1 = *(const uint4*)(bb + 48);
      float Bv[16];
      UNPK8(Bv, 0, B0)
      UNPK8(Bv, 8, B1)
#pragma unroll
      for (int n = 0; n < 16; ++n) {
        float a = __builtin_amdgcn_exp2f(dtt * Ac2[n]);
        h[n] = fmaf(h[n], a, dx * Bv[n]);
      }
    }
  }
  unsigned up[16];
#pragma unroll
  for (int n = 0; n < 16; ++n)
    up[n] = pkbf(h[n], __builtin_amdgcn_exp2f(Ac2[n] * sdt));
  uint4* hp4 = (uint4*)(hpk + (((size_t)b * NCH4 + c) * DINNER + d) * 16);
#pragma unroll
  for (int q = 0; q < 4; ++q) hp4[q] = *(uint4*)&up[q * 4];
}

// ---------------------------------------------------------------------------
// K6b: sequential chunk-boundary propagation
// ---------------------------------------------------------------------------
__global__ __launch_bounds__(256) void scan_part2(
    const unsigned* __restrict__ hpk, ushortT* __restrict__ hinb) {
  int e = blockIdx.x * 256 + threadIdx.x;   // [0, 6144)
  int b = blockIdx.y;
  float H = 0.f;
  size_t base = (size_t)b * NCH4 * (DINNER * DSTATE) + e;
#pragma unroll 16
  for (int c = 0; c < NCH4; ++c) {
    size_t idx = base + (size_t)c * (DINNER * DSTATE);
    unsigned w = hpk[idx];
    __hip_bfloat16 hb = __float2bfloat16(H);
    hinb[idx] = *(ushortT*)&hb;
    H = fmaf(bfhi(w), H, bflo(w));   // pa = hi, h_end = lo
  }
}

// ---------------------------------------------------------------------------
// K6c: seeded chunk scan -> y (in-lane C-dot) + D-skip + SiLU gate -> ybuf
// ---------------------------------------------------------------------------
__global__ __launch_bounds__(384) void scan_part3(
    const unsigned* __restrict__ dxpk, const ushortT* __restrict__ dbc,
    const __hip_bfloat16* __restrict__ xz, const float* __restrict__ A_log,
    const float* __restrict__ Dvec, const ushortT* __restrict__ hinb,
    __hip_bfloat16* __restrict__ ybuf) {
  __shared__ ushortT dbc_s[16 * 48];
  int d = threadIdx.x, c = blockIdx.x, b = blockIdx.y;
  size_t rowbase = (size_t)b * LSEQ + (size_t)c * LC4;
  if (d < 96) {
    int row = d / 6, q = d % 6;
    ((uint4*)dbc_s)[d] = ((const uint4*)(dbc + (rowbase + row) * 48))[q];
  }
  float Ac2[16];
#pragma unroll
  for (int q = 0; q < 4; ++q) {
    float4 t4 = *(const float4*)(A_log + d * 16 + q * 4);
    Ac2[q * 4 + 0] = -__expf(t4.x) * 1.44269504f;
    Ac2[q * 4 + 1] = -__expf(t4.y) * 1.44269504f;
    Ac2[q * 4 + 2] = -__expf(t4.z) * 1.44269504f;
    Ac2[q * 4 + 3] = -__expf(t4.w) * 1.44269504f;
  }
  float h[16];
  {
    const uint4* hp = (const uint4*)(hinb + (((size_t)b * NCH4 + c) * DINNER + d) * 16);
    uint4 h0 = hp[0], h1 = hp[1];
    UNPK8(h, 0, h0)
    UNPK8(h, 8, h1)
  }
  float Dd = Dvec[d];
  const unsigned* pkp = dxpk + rowbase * DINNER + d;
  const ushortT* zp = (const ushortT*)xz + rowbase * XZW + DINNER + d;
  __hip_bfloat16* yp = ybuf + rowbase * DINNER + d;
  __syncthreads();
#pragma unroll
  for (int t0 = 0; t0 < 16; t0 += 4) {
    unsigned pk[4];
    ushortT zv4[4];
#pragma unroll
    for (int j = 0; j < 4; ++j) {
      pk[j] = pkp[(t0 + j) * DINNER];
      zv4[j] = zp[(t0 + j) * XZW];
    }
#pragma unroll
    for (int j = 0; j < 4; ++j) {
      int t = t0 + j;
      float dtt = bflo(pk[j]), xmv = bfhi(pk[j]);
      float dx = dtt * xmv;
      const char* bb = (const char*)dbc_s + t * 96;
      uint4 B0 = *(const uint4*)(bb + 32);
      uint4 B1 = *(const uint4*)(bb + 48);
      uint4 C0 = *(const uint4*)(bb + 64);
      uint4 C1 = *(const uint4*)(bb + 80);
      float Bv[16], Cw[16];
      UNPK8(Bv, 0, B0)
      UNPK8(Bv, 8, B1)
      UNPK8(Cw, 0, C0)
      UNPK8(Cw, 8, C1)
      float y0 = 0.f, y1 = 0.f, y2 = 0.f, y3 = 0.f;
#pragma unroll
      for (int n = 0; n < 16; n += 4) {
        float a0 = __builtin_amdgcn_exp2f(dtt * Ac2[n + 0]);
        float a1 = __builtin_amdgcn_exp2f(dtt * Ac2[n + 1]);
        float a2 = __builtin_amdgcn_exp2f(dtt * Ac2[n + 2]);
        float a3 = __builtin_amdgcn_exp2f(dtt * Ac2[n + 3]);
        h[n + 0] = fmaf(h[n + 0], a0, dx * Bv[n + 0]);
        h[n + 1] = fmaf(h[n + 1], a1, dx * Bv[n + 1]);
        h[n + 2] = fmaf(h[n + 2], a2, dx * Bv[n + 2]);
        h[n + 3] = fmaf(h[n + 3], a3, dx * Bv[n + 3]);
        y0 = fmaf(h[n + 0], Cw[n + 0], y0);
        y1 = fmaf(h[n + 1], Cw[n + 1], y1);
        y2 = fmaf(h[n + 2], Cw[n + 2], y2);
        y3 = fmaf(h[n + 3], Cw[n + 3], y3);
      }
      float yv = fmaf(xmv, Dd, (y0 + y1) + (y2 + y3));
      float zv = bf2f(zv4[j]);
      float gt = zv * __builtin_amdgcn_rcpf(
          1.f + __builtin_amdgcn_exp2f(zv * -1.44269504f));
      yp[(size_t)t * DINNER] = __float2bfloat16(yv * gt);
    }
  }
}

// ---------------------------------------------------------------------------
extern "C" void kernel_launch(void* const* d_in, const int* in_sizes, int n_in,
                              void* d_out, int out_size, void* d_ws, size_t ws_size,
                              hipStream_t stream) {
  const float* x        = (const float*)d_in[0];
  const float* ln_w     = (const float*)d_in[1];
  const float* ln_b     = (const float*)d_in[2];
  const float* in_proj  = (const float*)d_in[3];   // [768,192]
  const float* conv_w   = (const float*)d_in[4];   // [384,4]
  const float* conv_b   = (const float*)d_in[5];   // [384]
  const float* x_proj   = (const float*)d_in[6];   // [44,384]
  const float* dt_w     = (const float*)d_in[7];   // [384,12]
  const float* dt_b     = (const float*)d_in[8];   // [384]
  const float* A_log    = (const float*)d_in[9];   // [384,16]
  const float* Dvec     = (const float*)d_in[10];  // [384]
  const float* out_proj = (const float*)d_in[11];  // [192,384]
  float* out = (float*)d_out;

  // workspace layout (float units), ~122 MB
  float* ws = (float*)d_ws;
  __hip_bfloat16* xzb  = (__hip_bfloat16*)ws;                    // [16384][768] bf16
  __hip_bfloat16* xmh  = (__hip_bfloat16*)(ws + 6291456);        // [16384][384] bf16
  ushortT*        dbcb = (ushortT*)(ws + 9437184);               // [16384][48] bf16
  unsigned*       dxpk = (unsigned*)(ws + 9830400);              // [16384][384] u32 (dt,xm)
  unsigned*       hpk  = (unsigned*)(ws + 16121856);             // [4][256][384][16] u32
  ushortT*        hinb = (ushortT*)(ws + 22413312);              // same shape bf16
  __hip_bfloat16* ybuf = (__hip_bfloat16*)(ws + 25559040);       // [16384][384] bf16
  __hip_bfloat16* xnbf = (__hip_bfloat16*)(ws + 28704768);       // [16384][192] bf16
  __hip_bfloat16* wbf  = (__hip_bfloat16*)(ws + 30277632);       // 221184 bf16
  __hip_bfloat16* wcb  = (__hip_bfloat16*)(ws + 30388224);       // 448*384 bf16

  const ushortT* win  = (const ushortT*)wbf;             // [768][192]
  const ushortT* wout = (const ushortT*)(wbf + 147456);  // [192][384]

  prep_kernel<<<1536, 256, 0, stream>>>(in_proj, out_proj, x_proj, dt_w, wbf, wcb);

  ln_kernel<<<BSZ * HSP, 512, 0, stream>>>(x, ln_w, ln_b, xnbf);

  // in_proj: [16384,192] x [768,192]^T -> xzb bf16 [16384,768]  (BM=128,BN=128)
  gemm_bf16<2, 2, 4, 4, 2><<<dim3(NTOK / 128, XZW / 128), 256, 0, stream>>>(
      (const ushortT*)xnbf, win, xzb, nullptr, nullptr, nullptr, nullptr,
      DIMC, XZW, XZW);

  conv_silu_kernel<<<(NTOK * DINNER / 8) / 256, 256, 0, stream>>>(
      xzb, conv_w, conv_b, xmh);

  // fused x_proj + dt_proj + softplus + pack: [16384,384] x [448,384]^T
  gemm_bf16<2, 2, 4, 2, 4><<<dim3(NTOK / 128, NXP / 64), 256, 0, stream>>>(
      (const ushortT*)xmh, (const ushortT*)wcb, dxpk, dbcb,
      (const ushortT*)xmh, dt_b, nullptr, DINNER, NXP, 0);

  scan_part1<<<dim3(NCH4, BSZ), 384, 0, stream>>>(dxpk, dbcb, A_log, hpk);
  scan_part2<<<dim3(DINNER * DSTATE / 256, BSZ), 256, 0, stream>>>(hpk, hinb);
  scan_part3<<<dim3(NCH4, BSZ), 384, 0, stream>>>(
      dxpk, dbcb, xzb, A_log, Dvec, hinb, ybuf);

  // out_proj: A=w_out[192][384], B=ybuf[b][4096][384] -> out[b][192][4096] + residual
  gemm_bf16<2, 2, 2, 4, 1><<<dim3(DIMC / 64, LSEQ / 128, BSZ), 256, 0, stream>>>(
      wout, (const ushortT*)ybuf, out, nullptr, nullptr, nullptr, x,
      DINNER, LSEQ, LSEQ);
}

// Round 11
// 141.881 us; speedup vs baseline: 1.5172x; 1.0909x over previous
//
#include <hip/hip_runtime.h>
#include <hip/hip_bf16.h>
#include <cstdint>
#include <cmath>

#define DIMC   192
#define DSTATE 16
#define DCONV  4
#define DINNER 384
#define DTRANK 12
#define BSZ    4
#define HSP    64
#define WSP    64
#define LSEQ   4096
#define NTOK   (BSZ*LSEQ)            // 16384
#define XZW    (2*DINNER)            // 768
#define LC5    32                    // scan chunk length
#define NCH5   (LSEQ/LC5)            // 128 chunks per batch
#define NXP    448                   // padded fused x_proj+dt output width

typedef unsigned short ushortT;
using short8 = __attribute__((ext_vector_type(8))) short;
using f32x4  = __attribute__((ext_vector_type(4))) float;

typedef unsigned int u32_as1 __attribute__((address_space(1)));
typedef unsigned int u32_as3 __attribute__((address_space(3)));

// async global->LDS DMA, 16 B per lane (lane i writes ldsbase + 16*i)
__device__ __forceinline__ void gl_lds16(const ushortT* g, ushortT* l) {
  __builtin_amdgcn_global_load_lds((const u32_as1*)g, (u32_as3*)l, 16, 0, 0);
}

__device__ __forceinline__ float bflo(unsigned u) { return __uint_as_float(u << 16); }
__device__ __forceinline__ float bfhi(unsigned u) { return __uint_as_float(u & 0xffff0000u); }
__device__ __forceinline__ float bf2f(ushortT u) { return __uint_as_float(((unsigned)u) << 16); }
__device__ __forceinline__ unsigned pkbf(float lo, float hi) {
  __hip_bfloat16 l = __float2bfloat16(lo), h = __float2bfloat16(hi);
  return (unsigned)*(ushortT*)&l | ((unsigned)*(ushortT*)&h << 16);
}
#define UNPK8(arr, base, v4)                                        \
  arr[base + 0] = bflo(v4.x); arr[base + 1] = bfhi(v4.x);           \
  arr[base + 2] = bflo(v4.y); arr[base + 3] = bfhi(v4.y);           \
  arr[base + 4] = bflo(v4.z); arr[base + 5] = bfhi(v4.z);           \
  arr[base + 6] = bflo(v4.w); arr[base + 7] = bfhi(v4.w);

// ---------------------------------------------------------------------------
// K1: merged LN + weight prep.
//   blocks [0,256): [B,C,H,W] -> LayerNorm over C -> xn_bf16 [B*L, C]
//   blocks [256,1024): f32->bf16 weights + combined [448][384] x_proj/dt fold
// ---------------------------------------------------------------------------
__global__ __launch_bounds__(512) void ln_prep_kernel(
    const float* __restrict__ x, const float* __restrict__ ln_w,
    const float* __restrict__ ln_b, const float* __restrict__ w_in,
    const float* __restrict__ w_out, const float* __restrict__ xpw,
    const float* __restrict__ dtw, __hip_bfloat16* __restrict__ xn,
    __hip_bfloat16* __restrict__ wbf, __hip_bfloat16* __restrict__ wcb) {
  if (blockIdx.x >= 256) {
    int gid = (blockIdx.x - 256) * 512 + threadIdx.x;   // < 393216
    if (gid < 221184) {
      float v = gid < 147456 ? w_in[gid] : w_out[gid - 147456];
      wbf[gid] = __float2bfloat16(v);
    } else {
      int e = gid - 221184;                             // < 172032
      int dd = e / 384, k = e % 384;
      float v = 0.f;
      if (dd < 384) {
#pragma unroll
        for (int j = 0; j < 12; ++j) v = fmaf(dtw[dd * 12 + j], xpw[j * 384 + k], v);
      } else if (dd < 416) {
        v = xpw[(dd - 372) * 384 + k];
      }
      wcb[e] = __float2bfloat16(v);
    }
    return;
  }
  __shared__ float xs[DIMC][WSP + 1];
  __shared__ float mu_s[WSP], rs_s[WSP];
  int bh = blockIdx.x;
  int b = bh >> 6, h = bh & 63;
  int tid = threadIdx.x;
  const float* xb = x + (size_t)b * DIMC * LSEQ + (size_t)h * WSP;
  for (int e = tid; e < DIMC * WSP; e += 512) {
    int c = e >> 6, w = e & 63;
    xs[c][w] = xb[(size_t)c * LSEQ + w];
  }
  __syncthreads();
  {
    int w = tid >> 3, p = tid & 7;
    float s = 0.f, s2 = 0.f;
#pragma unroll
    for (int i = 0; i < 24; ++i) {
      float v = xs[p * 24 + i][w];
      s += v; s2 = fmaf(v, v, s2);
    }
    s  += __shfl_xor(s, 1);  s2 += __shfl_xor(s2, 1);
    s  += __shfl_xor(s, 2);  s2 += __shfl_xor(s2, 2);
    s  += __shfl_xor(s, 4);  s2 += __shfl_xor(s2, 4);
    if (p == 0) {
      float mu = s * (1.f / DIMC);
      float var = s2 * (1.f / DIMC) - mu * mu;
      mu_s[w] = mu;
      rs_s[w] = rsqrtf(var + 1e-5f);
    }
  }
  __syncthreads();
  __hip_bfloat16* xo = xn + (size_t)(b * LSEQ + h * WSP) * DIMC;
  for (int e = tid; e < DIMC * WSP; e += 512) {
    int w = e / DIMC, c = e % DIMC;
    xo[(size_t)w * DIMC + c] =
        __float2bfloat16((xs[c][w] - mu_s[w]) * rs_s[w] * ln_w[c] + ln_b[c]);
  }
}

// ---------------------------------------------------------------------------
// bf16 MFMA GEMM with global_load_lds DMA staging + XOR-swizzled LDS.
// (unchanged from round 10 — proven)
// ---------------------------------------------------------------------------
template<int WM, int WN, int FM, int FN, int EPI>
__global__ __launch_bounds__(256) void gemm_bf16(
    const ushortT* __restrict__ A, const ushortT* __restrict__ B,
    void* __restrict__ Cv, void* __restrict__ Cv2,
    const ushortT* __restrict__ xm_aux, const float* __restrict__ bias384,
    const float* __restrict__ xres, int K, int Nreal, int ldc) {
  constexpr int BM = WM * FM * 16, BN = WN * FN * 16;
  __shared__ ushortT As[BM][64];
  __shared__ ushortT Bs[BN][64];
  __shared__ float Ct[(EPI == 1) ? (BM * (BN + 4)) : 1];
  int bm = blockIdx.x * BM, bn = blockIdx.y * BN;
  int tid = threadIdx.x, lane = tid & 63, w = tid >> 6;
  int wm = w / WN, wn = w % WN;
  int lm = lane & 15, lk = lane >> 4;
  int sub = lane >> 3, slot = lane & 7;      // 8 rows x 8 slots per DMA inst
  const ushortT* Bb = B;
  size_t zoff = 0;
  if constexpr (EPI == 1) {
    size_t zb = blockIdx.z;
    Bb = B + zb * (size_t)LSEQ * K;
    zoff = zb * (size_t)DIMC * LSEQ;
  }
  f32x4 acc[FM][FN];
#pragma unroll
  for (int mi = 0; mi < FM; ++mi)
#pragma unroll
    for (int ni = 0; ni < FN; ++ni) acc[mi][ni] = (f32x4){0.f, 0.f, 0.f, 0.f};

  for (int k0 = 0; k0 < K; k0 += 64) {
    __syncthreads();
#pragma unroll
    for (int j = 0; j < BM / 32; ++j) {
      int row = w * (BM / 4) + j * 8;
      gl_lds16(A + (size_t)(bm + row + sub) * K + k0 + ((slot ^ sub) << 3),
               &As[row][0]);
    }
#pragma unroll
    for (int j = 0; j < BN / 32; ++j) {
      int row = w * (BN / 4) + j * 8;
      gl_lds16(Bb + (size_t)(bn + row + sub) * K + k0 + ((slot ^ sub) << 3),
               &Bs[row][0]);
    }
    __syncthreads();   // drains the LDS-DMA (vmcnt) before reads
#pragma unroll
    for (int ks = 0; ks < 2; ++ks) {
      short8 af[FM], bfr[FN];
#pragma unroll
      for (int mi = 0; mi < FM; ++mi) {
        int row = wm * FM * 16 + mi * 16 + lm;
        int col = (ks * 64 + lk * 16) ^ ((lm & 7) << 4);
        af[mi] = *(const short8*)((const char*)As + row * 128 + col);
      }
#pragma unroll
      for (int ni = 0; ni < FN; ++ni) {
        int row = wn * FN * 16 + ni * 16 + lm;
        int col = (ks * 64 + lk * 16) ^ ((lm & 7) << 4);
        bfr[ni] = *(const short8*)((const char*)Bs + row * 128 + col);
      }
#pragma unroll
      for (int mi = 0; mi < FM; ++mi)
#pragma unroll
        for (int ni = 0; ni < FN; ++ni)
          acc[mi][ni] = __builtin_amdgcn_mfma_f32_16x16x32_bf16(
              af[mi], bfr[ni], acc[mi][ni], 0, 0, 0);
    }
  }

  if constexpr (EPI == 1) {
    __syncthreads();
    float (*CtA)[BN + 4] = (float(*)[BN + 4])Ct;
#pragma unroll
    for (int mi = 0; mi < FM; ++mi)
#pragma unroll
      for (int ni = 0; ni < FN; ++ni)
#pragma unroll
        for (int r = 0; r < 4; ++r)
          CtA[wm * FM * 16 + mi * 16 + lk * 4 + r][wn * FN * 16 + ni * 16 + lm] =
              acc[mi][ni][r];
    __syncthreads();
    float* Cout = (float*)Cv;
    for (int e = tid; e < BM * (BN / 4); e += 256) {
      int row = e / (BN / 4), q = e % (BN / 4);
      size_t gidx = zoff + (size_t)(bm + row) * LSEQ + bn + q * 4;
      float4 rv = *(const float4*)(xres + gidx);
      float4 o;
      o.x = CtA[row][q * 4 + 0] + rv.x;
      o.y = CtA[row][q * 4 + 1] + rv.y;
      o.z = CtA[row][q * 4 + 2] + rv.z;
      o.w = CtA[row][q * 4 + 3] + rv.w;
      *(float4*)(Cout + gidx) = o;
    }
  } else {
#pragma unroll
    for (int mi = 0; mi < FM; ++mi) {
#pragma unroll
      for (int ni = 0; ni < FN; ++ni) {
        int ncol = bn + wn * FN * 16 + ni * 16 + lm;
#pragma unroll
        for (int r = 0; r < 4; ++r) {
          int m = bm + wm * FM * 16 + mi * 16 + lk * 4 + r;
          if constexpr (EPI == 2) {
            if (ncol < Nreal)
              ((__hip_bfloat16*)Cv)[(size_t)m * ldc + ncol] =
                  __float2bfloat16(acc[mi][ni][r]);
          } else {  // EPI 4
            if (ncol < 384) {
              float dtr = acc[mi][ni][r] + bias384[ncol];
              float dt = dtr > 15.f ? dtr : __logf(1.f + __expf(dtr));
              float xmv = bf2f(xm_aux[(size_t)m * DINNER + ncol]);
              ((unsigned*)Cv)[(size_t)m * DINNER + ncol] = pkbf(dt, xmv);
            } else if (ncol < 416) {
              __hip_bfloat16 bv = __float2bfloat16(acc[mi][ni][r]);
              ((ushortT*)Cv2)[(size_t)m * 48 + 16 + (ncol - 384)] = *(ushortT*)&bv;
            }
          }
        }
      }
    }
  }
}

// ---------------------------------------------------------------------------
// K3: causal depthwise conv (k=4) + bias + SiLU, 8 channels per thread
// ---------------------------------------------------------------------------
__global__ __launch_bounds__(256) void conv_silu_kernel(
    const __hip_bfloat16* __restrict__ xz, const float* __restrict__ conv_w,
    const float* __restrict__ conv_b, __hip_bfloat16* __restrict__ xmh) {
  int g8 = blockIdx.x * 256 + threadIdx.x;      // < NTOK*384/8
  int d8 = g8 % 48;
  int tok = g8 / 48;
  int l = tok & (LSEQ - 1);
  int d0 = d8 * 8;
  const ushortT* base = (const ushortT*)xz + (size_t)tok * XZW + d0;
  uint4 r0, r1, r2, r3;
  r3 = *(const uint4*)(base);
  r2 = l >= 1 ? *(const uint4*)(base - XZW)     : (uint4){0, 0, 0, 0};
  r1 = l >= 2 ? *(const uint4*)(base - 2 * XZW) : (uint4){0, 0, 0, 0};
  r0 = l >= 3 ? *(const uint4*)(base - 3 * XZW) : (uint4){0, 0, 0, 0};
  float x0[8], x1[8], x2[8], x3[8];
  UNPK8(x0, 0, r0) UNPK8(x1, 0, r1) UNPK8(x2, 0, r2) UNPK8(x3, 0, r3)
  ushortT outv[8];
#pragma unroll
  for (int j = 0; j < 8; ++j) {
    const float4 w = *(const float4*)(conv_w + (d0 + j) * 4);
    float acc = conv_b[d0 + j];
    acc = fmaf(w.x, x0[j], acc);
    acc = fmaf(w.y, x1[j], acc);
    acc = fmaf(w.z, x2[j], acc);
    acc = fmaf(w.w, x3[j], acc);
    float s = acc / (1.f + __expf(-acc));
    __hip_bfloat16 sb = __float2bfloat16(s);
    outv[j] = *(ushortT*)&sb;
  }
  *(uint4*)((ushortT*)xmh + (size_t)tok * DINNER + d0) = *(uint4*)outv;
}

// ---------------------------------------------------------------------------
// K6a: chunk-local scan (LC=32): h_end from 0 + decay product -> packed u32
// ---------------------------------------------------------------------------
__global__ __launch_bounds__(384) void scan_part1(
    const unsigned* __restrict__ dxpk, const ushortT* __restrict__ dbc,
    const float* __restrict__ A_log, unsigned* __restrict__ hpk) {
  __shared__ ushortT dbc_s[32 * 48];
  int d = threadIdx.x, c = blockIdx.x, b = blockIdx.y;
  size_t rowbase = (size_t)b * LSEQ + (size_t)c * LC5;
  if (d < 192) {
    int row = d / 6, q = d % 6;
    ((uint4*)dbc_s)[d] = ((const uint4*)(dbc + (rowbase + row) * 48))[q];
  }
  float Ac2[16];
#pragma unroll
  for (int q = 0; q < 4; ++q) {
    float4 t4 = *(const float4*)(A_log + d * 16 + q * 4);
    Ac2[q * 4 + 0] = -__expf(t4.x) * 1.44269504f;
    Ac2[q * 4 + 1] = -__expf(t4.y) * 1.44269504f;
    Ac2[q * 4 + 2] = -__expf(t4.z) * 1.44269504f;
    Ac2[q * 4 + 3] = -__expf(t4.w) * 1.44269504f;
  }
  float h[16];
#pragma unroll
  for (int n = 0; n < 16; ++n) h[n] = 0.f;
  float sdt = 0.f;
  const unsigned* pkp = dxpk + rowbase * DINNER + d;
  __syncthreads();
#pragma unroll
  for (int t0 = 0; t0 < LC5; t0 += 4) {
    unsigned pk[4];
#pragma unroll
    for (int j = 0; j < 4; ++j) pk[j] = pkp[(t0 + j) * DINNER];
#pragma unroll
    for (int j = 0; j < 4; ++j) {
      int t = t0 + j;
      float dtt = bflo(pk[j]), xmv = bfhi(pk[j]);
      sdt += dtt;
      float dx = dtt * xmv;
      const char* bb = (const char*)dbc_s + t * 96;
      uint4 B0 = *(const uint4*)(bb + 32);
      uint4 B1 = *(const uint4*)(bb + 48);
      float Bv[16];
      UNPK8(Bv, 0, B0)
      UNPK8(Bv, 8, B1)
#pragma unroll
      for (int n = 0; n < 16; ++n) {
        float a = __builtin_amdgcn_exp2f(dtt * Ac2[n]);
        h[n] = fmaf(h[n], a, dx * Bv[n]);
      }
    }
  }
  unsigned up[16];
#pragma unroll
  for (int n = 0; n < 16; ++n)
    up[n] = pkbf(h[n], __builtin_amdgcn_exp2f(Ac2[n] * sdt));
  uint4* hp4 = (uint4*)(hpk + (((size_t)b * NCH5 + c) * DINNER + d) * 16);
#pragma unroll
  for (int q = 0; q < 4; ++q) hp4[q] = *(uint4*)&up[q * 4];
}

// ---------------------------------------------------------------------------
// K6b: sequential chunk-boundary propagation (128 steps)
// ---------------------------------------------------------------------------
__global__ __launch_bounds__(256) void scan_part2(
    const unsigned* __restrict__ hpk, ushortT* __restrict__ hinb) {
  int e = blockIdx.x * 256 + threadIdx.x;   // [0, 6144)
  int b = blockIdx.y;
  float H = 0.f;
  size_t base = (size_t)b * NCH5 * (DINNER * DSTATE) + e;
#pragma unroll 16
  for (int c = 0; c < NCH5; ++c) {
    size_t idx = base + (size_t)c * (DINNER * DSTATE);
    unsigned w = hpk[idx];
    __hip_bfloat16 hb = __float2bfloat16(H);
    hinb[idx] = *(ushortT*)&hb;
    H = fmaf(bfhi(w), H, bflo(w));   // pa = hi, h_end = lo
  }
}

// ---------------------------------------------------------------------------
// K6c: seeded chunk scan (LC=32) -> y (in-lane C-dot) + D-skip + SiLU -> ybuf
// ---------------------------------------------------------------------------
__global__ __launch_bounds__(384) void scan_part3(
    const unsigned* __restrict__ dxpk, const ushortT* __restrict__ dbc,
    const __hip_bfloat16* __restrict__ xz, const float* __restrict__ A_log,
    const float* __restrict__ Dvec, const ushortT* __restrict__ hinb,
    __hip_bfloat16* __restrict__ ybuf) {
  __shared__ ushortT dbc_s[32 * 48];
  int d = threadIdx.x, c = blockIdx.x, b = blockIdx.y;
  size_t rowbase = (size_t)b * LSEQ + (size_t)c * LC5;
  if (d < 192) {
    int row = d / 6, q = d % 6;
    ((uint4*)dbc_s)[d] = ((const uint4*)(dbc + (rowbase + row) * 48))[q];
  }
  float Ac2[16];
#pragma unroll
  for (int q = 0; q < 4; ++q) {
    float4 t4 = *(const float4*)(A_log + d * 16 + q * 4);
    Ac2[q * 4 + 0] = -__expf(t4.x) * 1.44269504f;
    Ac2[q * 4 + 1] = -__expf(t4.y) * 1.44269504f;
    Ac2[q * 4 + 2] = -__expf(t4.z) * 1.44269504f;
    Ac2[q * 4 + 3] = -__expf(t4.w) * 1.44269504f;
  }
  float h[16];
  {
    const uint4* hp = (const uint4*)(hinb + (((size_t)b * NCH5 + c) * DINNER + d) * 16);
    uint4 h0 = hp[0], h1 = hp[1];
    UNPK8(h, 0, h0)
    UNPK8(h, 8, h1)
  }
  float Dd = Dvec[d];
  const unsigned* pkp = dxpk + rowbase * DINNER + d;
  const ushortT* zp = (const ushortT*)xz + rowbase * XZW + DINNER + d;
  __hip_bfloat16* yp = ybuf + rowbase * DINNER + d;
  __syncthreads();
#pragma unroll
  for (int t0 = 0; t0 < LC5; t0 += 4) {
    unsigned pk[4];
    ushortT zv4[4];
#pragma unroll
    for (int j = 0; j < 4; ++j) {
      pk[j] = pkp[(t0 + j) * DINNER];
      zv4[j] = zp[(t0 + j) * XZW];
    }
#pragma unroll
    for (int j = 0; j < 4; ++j) {
      int t = t0 + j;
      float dtt = bflo(pk[j]), xmv = bfhi(pk[j]);
      float dx = dtt * xmv;
      const char* bb = (const char*)dbc_s + t * 96;
      uint4 B0 = *(const uint4*)(bb + 32);
      uint4 B1 = *(const uint4*)(bb + 48);
      uint4 C0 = *(const uint4*)(bb + 64);
      uint4 C1 = *(const uint4*)(bb + 80);
      float Bv[16], Cw[16];
      UNPK8(Bv, 0, B0)
      UNPK8(Bv, 8, B1)
      UNPK8(Cw, 0, C0)
      UNPK8(Cw, 8, C1)
      float y0 = 0.f, y1 = 0.f, y2 = 0.f, y3 = 0.f;
#pragma unroll
      for (int n = 0; n < 16; n += 4) {
        float a0 = __builtin_amdgcn_exp2f(dtt * Ac2[n + 0]);
        float a1 = __builtin_amdgcn_exp2f(dtt * Ac2[n + 1]);
        float a2 = __builtin_amdgcn_exp2f(dtt * Ac2[n + 2]);
        float a3 = __builtin_amdgcn_exp2f(dtt * Ac2[n + 3]);
        h[n + 0] = fmaf(h[n + 0], a0, dx * Bv[n + 0]);
        h[n + 1] = fmaf(h[n + 1], a1, dx * Bv[n + 1]);
        h[n + 2] = fmaf(h[n + 2], a2, dx * Bv[n + 2]);
        h[n + 3] = fmaf(h[n + 3], a3, dx * Bv[n + 3]);
        y0 = fmaf(h[n + 0], Cw[n + 0], y0);
        y1 = fmaf(h[n + 1], Cw[n + 1], y1);
        y2 = fmaf(h[n + 2], Cw[n + 2], y2);
        y3 = fmaf(h[n + 3], Cw[n + 3], y3);
      }
      float yv = fmaf(xmv, Dd, (y0 + y1) + (y2 + y3));
      float zv = bf2f(zv4[j]);
      float gt = zv * __builtin_amdgcn_rcpf(
          1.f + __builtin_amdgcn_exp2f(zv * -1.44269504f));
      yp[(size_t)t * DINNER] = __float2bfloat16(yv * gt);
    }
  }
}

// ---------------------------------------------------------------------------
extern "C" void kernel_launch(void* const* d_in, const int* in_sizes, int n_in,
                              void* d_out, int out_size, void* d_ws, size_t ws_size,
                              hipStream_t stream) {
  const float* x        = (const float*)d_in[0];
  const float* ln_w     = (const float*)d_in[1];
  const float* ln_b     = (const float*)d_in[2];
  const float* in_proj  = (const float*)d_in[3];   // [768,192]
  const float* conv_w   = (const float*)d_in[4];   // [384,4]
  const float* conv_b   = (const float*)d_in[5];   // [384]
  const float* x_proj   = (const float*)d_in[6];   // [44,384]
  const float* dt_w     = (const float*)d_in[7];   // [384,12]
  const float* dt_b     = (const float*)d_in[8];   // [384]
  const float* A_log    = (const float*)d_in[9];   // [384,16]
  const float* Dvec     = (const float*)d_in[10];  // [384]
  const float* out_proj = (const float*)d_in[11];  // [192,384]
  float* out = (float*)d_out;

  // workspace layout (float units), ~103 MB
  float* ws = (float*)d_ws;
  __hip_bfloat16* xzb  = (__hip_bfloat16*)ws;                    // [16384][768] bf16
  __hip_bfloat16* xmh  = (__hip_bfloat16*)(ws + 6291456);        // [16384][384] bf16
  ushortT*        dbcb = (ushortT*)(ws + 9437184);               // [16384][48] bf16
  unsigned*       dxpk = (unsigned*)(ws + 9830400);              // [16384][384] u32 (dt,xm)
  unsigned*       hpk  = (unsigned*)(ws + 16121856);             // [4][128][384][16] u32
  ushortT*        hinb = (ushortT*)(ws + 19267584);              // same shape bf16
  __hip_bfloat16* ybuf = (__hip_bfloat16*)(ws + 20840448);       // [16384][384] bf16
  __hip_bfloat16* xnbf = (__hip_bfloat16*)(ws + 23986176);       // [16384][192] bf16
  __hip_bfloat16* wbf  = (__hip_bfloat16*)(ws + 25559040);       // 221184 bf16
  __hip_bfloat16* wcb  = (__hip_bfloat16*)(ws + 25669632);       // 448*384 bf16

  const ushortT* win  = (const ushortT*)wbf;             // [768][192]
  const ushortT* wout = (const ushortT*)(wbf + 147456);  // [192][384]

  ln_prep_kernel<<<1024, 512, 0, stream>>>(
      x, ln_w, ln_b, in_proj, out_proj, x_proj, dt_w, xnbf, wbf, wcb);

  // in_proj: [16384,192] x [768,192]^T -> xzb bf16 [16384,768]  (BM=128,BN=128)
  gemm_bf16<2, 2, 4, 4, 2><<<dim3(NTOK / 128, XZW / 128), 256, 0, stream>>>(
      (const ushortT*)xnbf, win, xzb, nullptr, nullptr, nullptr, nullptr,
      DIMC, XZW, XZW);

  conv_silu_kernel<<<(NTOK * DINNER / 8) / 256, 256, 0, stream>>>(
      xzb, conv_w, conv_b, xmh);

  // fused x_proj + dt_proj + softplus + pack: [16384,384] x [448,384]^T
  gemm_bf16<2, 2, 4, 2, 4><<<dim3(NTOK / 128, NXP / 64), 256, 0, stream>>>(
      (const ushortT*)xmh, (const ushortT*)wcb, dxpk, dbcb,
      (const ushortT*)xmh, dt_b, nullptr, DINNER, NXP, 0);

  scan_part1<<<dim3(NCH5, BSZ), 384, 0, stream>>>(dxpk, dbcb, A_log, hpk);
  scan_part2<<<dim3(DINNER * DSTATE / 256, BSZ), 256, 0, stream>>>(hpk, hinb);
  scan_part3<<<dim3(NCH5, BSZ), 384, 0, stream>>>(
      dxpk, dbcb, xzb, A_log, Dvec, hinb, ybuf);

  // out_proj: A=w_out[192][384], B=ybuf[b][4096][384] -> out[b][192][4096] + residual
  gemm_bf16<2, 2, 2, 4, 1><<<dim3(DIMC / 64, LSEQ / 128, BSZ), 256, 0, stream>>>(
      wout, (const ushortT*)ybuf, out, nullptr, nullptr, nullptr, x,
      DINNER, LSEQ, LSEQ);
}